// Round 4
// baseline (1067.502 us; speedup 1.0000x reference)
//
#include <hip/hip_runtime.h>

// DGCN decomposition:
//   m = MLP(x[0])                       (tiny, fp32)
//   S = softmax(relu(E1 @ m @ E2^T))    (row softmax, fp32 -> bf16)
//   G1 = S @ X, G2 = S @ G1             (bf16 MFMA GEMMs, X = x as [m, (b,i,s)])
//   out[b,o,n,s] = bias[n,o] + sum_{k,i} Gk[n,(b,i,s)] * W[n,k,i,o]
// S^2 is never materialized (saves a 2048^3 GEMM).
//
// R7: k_gemm re-tiled 256x384 with 160 KiB LDS -> grid 8x32 = 256 blocks =
//   EXACTLY one residency round (kills the 1.5-round tail that capped R6 at
//   75%). 6 phases/K-tile (m-inner zigzag n0,n1,n2,n2,n1,n0; 3 live B-frag
//   sets -> 28 b128/wave/tile for 96 MFMA), staging staggered 2/phase,
//   counted gates vmcnt(2)/vmcnt(6) (never 0 in-loop), epilogue in two
//   96 KB half-passes. Everything else unchanged from R6.

typedef float  f32x4  __attribute__((ext_vector_type(4)));
typedef __bf16 bf16x8 __attribute__((ext_vector_type(8)));
typedef unsigned short u16;

#define GLOAD16(gp, lp) __builtin_amdgcn_global_load_lds( \
    (const __attribute__((address_space(1))) void*)(gp),  \
    (__attribute__((address_space(3))) void*)(lp), 16, 0, 0)

__device__ __forceinline__ u16 f2bf(float f){
  union { float f; unsigned u; } v; v.f = f;
  unsigned u = v.u;
  u += 0x7fffu + ((u >> 16) & 1u);   // round-to-nearest-even
  return (u16)(u >> 16);
}
__device__ __forceinline__ float bf2f(u16 h){
  union { unsigned u; float f; } v; v.u = ((unsigned)h) << 16;
  return v.f;
}
// unpack one uint (2 packed bf16) -> float2 {lo, hi} (lo = lower address)
__device__ __forceinline__ float2 unp2(unsigned u){
  union { unsigned q; float f; } a, b;
  a.q = u << 16; b.q = u & 0xffff0000u;
  return make_float2(a.f, b.f);
}

// ---------------- K1: h1[i,n] = tanh(x[0,i,n,:] . fc0_w + fc0_b) ----------------
__global__ void k_h1(const float* __restrict__ x, const float* __restrict__ fc0w,
                     const float* __restrict__ fc0b, float* __restrict__ h1){
  int g = blockIdx.x * 256 + threadIdx.x;        // g = i*2048 + n, 65536 total
  const float* xp = x + (long)g * 12;
  float s = fc0b[0];
  #pragma unroll
  for (int j = 0; j < 12; j++) s += xp[j] * fc0w[j];
  h1[g] = tanhf(s);
}

// ---------------- K2a: h2raw[i*16+d] = sum_n h1[i,n]*fc1_w[d,n] ----------------
__global__ __launch_bounds__(256) void k_h2a(const float* __restrict__ h1,
                                             const float* __restrict__ fc1w,
                                             float* __restrict__ h2raw){
  __shared__ float red[4];
  int id = blockIdx.x;                 // 0..511 = i*16+d
  int i = id >> 4, d = id & 15;
  int t = threadIdx.x;
  const float* hp = h1 + i * 2048;
  const float* wp = fc1w + d * 2048;
  float s = 0.f;
  for (int nn = t; nn < 2048; nn += 256) s += hp[nn] * wp[nn];
  for (int off = 32; off > 0; off >>= 1) s += __shfl_down(s, off, 64);
  if ((t & 63) == 0) red[t >> 6] = s;
  __syncthreads();
  if (t == 0) h2raw[id] = red[0] + red[1] + red[2] + red[3];
}

// ---------------- K2b: h2 = tanh(h2raw + fc1_b); m[d,e] = tanh(sum_i h2[i,d]*fc2_w[e,i] + fc2_b[e]) ----------------
__global__ void k_h2b(const float* __restrict__ h2raw, const float* __restrict__ fc1b,
                      const float* __restrict__ fc2w, const float* __restrict__ fc2b,
                      float* __restrict__ mmat){
  __shared__ float h2[512];
  int t = threadIdx.x;                 // 512 threads
  {
    int d = t & 15;
    h2[t] = tanhf(h2raw[t] + fc1b[d]);
  }
  __syncthreads();
  if (t < 256){
    int dd = t >> 4, e = t & 15;
    float s2 = fc2b[e];
    #pragma unroll
    for (int ii = 0; ii < 32; ii++) s2 += h2[ii * 16 + dd] * fc2w[e * 32 + ii];
    mmat[dd * 16 + e] = tanhf(s2);
  }
}

// ---------------- K3: support row n = softmax_j(relu(sum_d' (E1[n]@m)[d'] * E2[j,d'])) -> bf16 ----------------
__global__ __launch_bounds__(256) void k_support(const float* __restrict__ E1,
                                                 const float* __restrict__ E2,
                                                 const float* __restrict__ mmat,
                                                 u16* __restrict__ sup){
  __shared__ float ml[256];
  __shared__ float tv[16];
  __shared__ float red[8];
  int n = blockIdx.x, t = threadIdx.x;
  ml[t] = mmat[t];
  __syncthreads();
  if (t < 16){
    float s = 0.f;
    const float* er = E1 + n * 16;
    #pragma unroll
    for (int d = 0; d < 16; d++) s += er[d] * ml[d * 16 + t];
    tv[t] = s;
  }
  __syncthreads();
  float lmax = -1e30f;
  float lv[8];
  #pragma unroll
  for (int p = 0; p < 8; p++){
    int j = t + p * 256;
    const float* e2 = E2 + j * 16;
    float s = 0.f;
    #pragma unroll
    for (int d = 0; d < 16; d++) s += tv[d] * e2[d];
    s = fmaxf(s, 0.f);                 // relu BEFORE softmax
    lv[p] = s;
    lmax = fmaxf(lmax, s);
  }
  for (int off = 32; off > 0; off >>= 1) lmax = fmaxf(lmax, __shfl_down(lmax, off, 64));
  if ((t & 63) == 0) red[t >> 6] = lmax;
  __syncthreads();
  if (t == 0) red[0] = fmaxf(fmaxf(red[0], red[1]), fmaxf(red[2], red[3]));
  __syncthreads();
  float mx = red[0];
  float lsum = 0.f;
  #pragma unroll
  for (int p = 0; p < 8; p++){ float e = __expf(lv[p] - mx); lv[p] = e; lsum += e; }
  for (int off = 32; off > 0; off >>= 1) lsum += __shfl_down(lsum, off, 64);
  if ((t & 63) == 0) red[4 + (t >> 6)] = lsum;
  __syncthreads();
  if (t == 0) red[4] = red[4] + red[5] + red[6] + red[7];
  __syncthreads();
  float inv = 1.f / red[4];
  #pragma unroll
  for (int p = 0; p < 8; p++) sup[(long)n * 2048 + t + p * 256] = f2bf(lv[p] * inv);
}

// ---------------- K4: fused Xb[m][c]=bf16(x), Xbt[c][m]=Xb[m][c] (reads x once) ----------------
__global__ __launch_bounds__(256) void k_xbt2(const float* __restrict__ x,
                                              u16* __restrict__ Xb,
                                              u16* __restrict__ Xbt){
  __shared__ u16 tile[64][65];
  int cT = blockIdx.x * 64;            // 192 tiles over 12288
  int mT = blockIdx.y * 64;            // 32 tiles over 2048
  int t = threadIdx.x;
  int r = t >> 6, cc = t & 63;
  int cg = cT + cc;
  int bi = cg / 12, s = cg - bi * 12;
  long xoff = (long)bi * 24576 + s;    // x[((bi)*2048 + m)*12 + s]
  #pragma unroll
  for (int p = 0; p < 16; p++){
    int rr = p * 4 + r;
    u16 v = f2bf(x[xoff + (long)(mT + rr) * 12]);
    tile[rr][cc] = v;
    Xb[(long)(mT + rr) * 12288 + cg] = v;
  }
  __syncthreads();
  #pragma unroll
  for (int p = 0; p < 16; p++){
    int rr = p * 4 + r;
    Xbt[(long)(cT + rr) * 2048 + mT + cc] = tile[cc][rr];
  }
}

// ---------------- K6: W[n,k,i,o] via float4 + L1 reuse (4 n per block share P slice) ----------------
__global__ __launch_bounds__(256) void k_wb2(const float* __restrict__ E1, const float* __restrict__ E2,
                                             const float* __restrict__ P1, const float* __restrict__ P2,
                                             const float* __restrict__ BP1, const float* __restrict__ BP2,
                                             float* __restrict__ W, float* __restrict__ biasN){
  int bid = blockIdx.x, t = threadIdx.x;
  if (bid < 6144){
    int nb = bid & 511, rb = bid >> 9;       // 512 n-blocks x 12 r-blocks
    int n = nb * 4 + (t >> 6);
    int r4 = rb * 64 + (t & 63);             // float4 index within 768
    const float* e1 = E1 + n * 16;
    const float* e2 = E2 + n * 16;
    f32x4 s = {0.f, 0.f, 0.f, 0.f};
    #pragma unroll
    for (int d = 0; d < 16; d++){
      f32x4 p1 = *(const f32x4*)(P1 + d * 3072 + r4 * 4);
      f32x4 p2 = *(const f32x4*)(P2 + d * 3072 + r4 * 4);
      s += p1 * e1[d] + p2 * e2[d];
    }
    *(f32x4*)(W + (long)n * 3072 + r4 * 4) = s;
  } else {
    int e = (bid - 6144) * 256 + t;          // 65536 bias outputs
    int n = e >> 5, o = e & 31;
    const float* e1 = E1 + n * 16;
    const float* e2 = E2 + n * 16;
    float s = 0.f;
    #pragma unroll
    for (int d = 0; d < 16; d++) s += e1[d] * BP1[d * 32 + o] + e2[d] * BP2[d * 32 + o];
    biasN[e] = s;
  }
}

// ---------------- GEMM: C[m][c] = sum_k A[m][k] * Bt[c][k]; 256x384 tile, 8 waves ----------------
// 256 blocks = exactly 1 residency round (160 KiB LDS, 1 block/CU). 6 phases
// per K-tile (BK=64), m-inner zigzag (n0,n1,n2 | n2,n1,n0) with 3 live B-frag
// sets; staging staggered 2 loads/phase; counted gates vmcnt(2) at tile start
// (A1,A3 stay in flight) and vmcnt(6) before the m1 A-reads. LDS XOR swizzle
// (T2) via pre-swizzled global source; setprio (T5); XCD swizzle (T1).
// Epilogue: swizzled transposed C-tile in LDS, two 96 KB half-passes.
__global__ __launch_bounds__(512, 2) void k_gemm(const u16* __restrict__ A,
                                                 const u16* __restrict__ Bt,
                                                 u16* __restrict__ Cd,
                                                 u16* __restrict__ Ct,
                                                 int writeT){
  // 160 KiB: buf layout (u16 elems): A [0,16384) = 256 rows x 64, B [16384,40960)
  // = 384 rows x 64; buf1 at +40960.
  __shared__ u16 lds[81920];
  int tid  = threadIdx.x;
  int wave = tid >> 6, lane = tid & 63;
  int l15 = lane & 15, q = lane >> 4, l7 = l15 & 7;
  int wm = wave >> 2, wn = wave & 3;   // 2 x 4 waves; wave-tile 128(m) x 96(c)

  // bijective XCD swizzle: lin 0..255; 4 consecutive slots per xcd share yN
  int lin  = blockIdx.y * 32 + blockIdx.x;   // 0..255
  int xcd  = lin & 7;
  int slot = lin >> 3;                 // 0..31
  int yN   = slot >> 2;                // 0..7   (m-tile)
  int xN   = (slot & 3) * 8 + xcd;     // 0..31  (c-tile)
  long mBase = (long)yN * 256;
  long cBase = (long)xN * 384;

  f32x4 acc[8][6];
  #pragma unroll
  for (int t2 = 0; t2 < 8; t2++)
    #pragma unroll
    for (int u2 = 0; u2 < 6; u2++) acc[t2][u2] = (f32x4){0.f, 0.f, 0.f, 0.f};

  // staging: per region (64 rows x 64 cols), chunk L = tid -> row = L>>3,
  // c_lds = L&7; source chunk pre-swizzled: cel = (tid&7) ^ ((tid>>3)&7)
  int Lrow = tid >> 3;
  int cel  = (tid & 7) ^ (Lrow & 7);
  const u16* gAp = A  + (mBase + Lrow) * 2048 + cel * 8;
  const u16* gBp = Bt + (cBase + Lrow) * 2048 + cel * 8;

  // region r: A at lds[nx + r*4096], B at lds[nx + 16384 + r*4096]
#define GL_A(nx, ko, r) GLOAD16(gAp + (r) * (64 * 2048) + (ko), \
                                lds + (nx) + (r) * 4096 + wave * 512)
#define GL_B(nx, ko, r) GLOAD16(gBp + (r) * (64 * 2048) + (ko), \
                                lds + (nx) + 16384 + (r) * 4096 + wave * 512)

#define LDA(dst, mq) do { \
    _Pragma("unroll") \
    for (int t2 = 0; t2 < 4; t2++){ \
      int row = wm * 128 + ((mq) * 4 + t2) * 16 + l15; \
      _Pragma("unroll") \
      for (int kk = 0; kk < 2; kk++) \
        dst[t2][kk] = *(const bf16x8*)&lds[bA + row * 64 + (((kk << 2) | q) ^ l7) * 8]; \
    } } while(0)

#define LDB(dst, nq2) do { \
    _Pragma("unroll") \
    for (int u2 = 0; u2 < 2; u2++){ \
      int row = wn * 96 + ((nq2) * 2 + u2) * 16 + l15; \
      _Pragma("unroll") \
      for (int kk = 0; kk < 2; kk++) \
        dst[u2][kk] = *(const bf16x8*)&lds[bB + row * 64 + (((kk << 2) | q) ^ l7) * 8]; \
    } } while(0)

#define MFMA_Q(AF, mq, BB, nb) do { \
    __builtin_amdgcn_s_setprio(1); \
    _Pragma("unroll") \
    for (int t2 = 0; t2 < 4; t2++) \
      _Pragma("unroll") \
      for (int u2 = 0; u2 < 2; u2++) \
        _Pragma("unroll") \
        for (int kk = 0; kk < 2; kk++) \
          acc[(mq) * 4 + t2][(nb) + u2] = __builtin_amdgcn_mfma_f32_16x16x32_bf16( \
              AF[t2][kk], BB[u2][kk], acc[(mq) * 4 + t2][(nb) + u2], 0, 0, 0); \
    __builtin_amdgcn_s_setprio(0); \
  } while(0)

  // prologue: stage tile 0 into buf0 (issue order B0..B5, A0, A2, A1, A3)
  GL_B(0, 0, 0); GL_B(0, 0, 1); GL_B(0, 0, 2);
  GL_B(0, 0, 3); GL_B(0, 0, 4); GL_B(0, 0, 5);
  GL_A(0, 0, 0); GL_A(0, 0, 2); GL_A(0, 0, 1); GL_A(0, 0, 3);

  for (int t = 0; t < 32; t++){
    const int bA = (t & 1) ? 40960 : 0;
    const int bB = bA + 16384;
    const int nx = (t & 1) ? 0 : 40960;
    const long ko = (long)((t + 1) & 31) * 64;   // t=31 wraps (dummy stage)
    bf16x8 aA0[4][2], aA1[4][2], bb0[2][2], bb1[2][2], bb2[2][2];
    // ---- gate G1: retire B0..B5,A0,A2 of tile t (A1,A3 may stay in flight) ----
    asm volatile("s_waitcnt vmcnt(2)" ::: "memory");
    __builtin_amdgcn_s_barrier();
    // ---- P0: (m0,n0); prefetch B0,B1 ----
    LDA(aA0, 0);
    LDB(bb0, 0);
    GL_B(nx, ko, 0); GL_B(nx, ko, 1);
    __builtin_amdgcn_s_barrier();
    MFMA_Q(aA0, 0, bb0, 0);
    __builtin_amdgcn_s_barrier();
    // ---- P1: (m0,n1); prefetch B2,B3 ----
    LDB(bb1, 1);
    GL_B(nx, ko, 2); GL_B(nx, ko, 3);
    __builtin_amdgcn_s_barrier();
    MFMA_Q(aA0, 0, bb1, 2);
    __builtin_amdgcn_s_barrier();
    // ---- P2: (m0,n2); prefetch B4,B5 ----
    LDB(bb2, 2);
    GL_B(nx, ko, 4); GL_B(nx, ko, 5);
    __builtin_amdgcn_s_barrier();
    MFMA_Q(aA0, 0, bb2, 4);
    // ---- gate G2: retire A1,A3 of tile t (new B0..B5 stay in flight) ----
    asm volatile("s_waitcnt vmcnt(6)" ::: "memory");
    __builtin_amdgcn_s_barrier();
    // ---- P3: (m1,n2); prefetch A0,A2 ----
    LDA(aA1, 1);
    GL_A(nx, ko, 0); GL_A(nx, ko, 2);
    __builtin_amdgcn_s_barrier();
    MFMA_Q(aA1, 1, bb2, 4);
    __builtin_amdgcn_s_barrier();
    // ---- P4: (m1,n1); prefetch A1,A3 ----
    GL_A(nx, ko, 1); GL_A(nx, ko, 3);
    __builtin_amdgcn_s_barrier();
    MFMA_Q(aA1, 1, bb1, 2);
    __builtin_amdgcn_s_barrier();
    // ---- P5: (m1,n0) ----
    MFMA_Q(aA1, 1, bb0, 0);
  }
  // drain the wrapped dummy prefetch before reusing LDS for the epilogue
  asm volatile("s_waitcnt vmcnt(0)" ::: "memory");
  __builtin_amdgcn_sched_barrier(0);
  __syncthreads();

  // ---- epilogue: transposed tile tileT[c][m] in LDS (swizzled), 2 half-passes ----
  // half hc covers c-local lc in [0,192): waves wn in {2hc, 2hc+1} own it.
  // elem off = lc*256 + chunk'*8 + (m&7); chunk' = (m>>3) ^ (lc&7) ^ ((lc>>3)&7)
  for (int hc = 0; hc < 2; hc++){
    if (hc) __syncthreads();           // previous half's stores done
    if ((wn >> 1) == hc){
      int wnl = wn & 1;
      #pragma unroll
      for (int t2 = 0; t2 < 8; t2++){
        int m0 = wm * 128 + t2 * 16 + q * 4;
        #pragma unroll
        for (int u2 = 0; u2 < 6; u2++){
          int lc = wnl * 96 + u2 * 16 + l15;
          ushort4 v = make_ushort4(f2bf(acc[t2][u2][0]), f2bf(acc[t2][u2][1]),
                                   f2bf(acc[t2][u2][2]), f2bf(acc[t2][u2][3]));
          int sw = ((m0 >> 3) ^ (lc & 7) ^ ((lc >> 3) & 7));
          *(ushort4*)&lds[lc * 256 + (sw << 3) + (m0 & 7)] = v;
        }
      }
    }
    __syncthreads();
    int rr = tid >> 5;          // 0..15
    int ch = tid & 31;          // 16B chunk index
    if (writeT){
      // Ct rows are c: 192 rows this half, 256 m contiguous, 512B coalesced
      #pragma unroll
      for (int p = 0; p < 12; p++){
        int r = p * 16 + rr;
        uint4 v = *(const uint4*)&lds[r * 256 + ((ch ^ (r & 7) ^ ((r >> 3) & 7)) << 3)];
        *(uint4*)&Ct[(cBase + hc * 192 + r) * 2048 + mBase + ch * 8] = v;
      }
    }
    // Cd rows are m: gather 8 c-column values (24 chunks of 8 c this half)
    if (ch < 24){
      #pragma unroll
      for (int p = 0; p < 16; p++){
        int m = p * 16 + rr;
        int msw = (m >> 3), ml = m & 7;
        unsigned w[4];
        #pragma unroll
        for (int jj = 0; jj < 4; jj++){
          int c0 = ch * 8 + jj * 2, c1 = c0 + 1;
          unsigned lo = lds[c0 * 256 + (((msw ^ (c0 & 7) ^ (ch & 7)) << 3)) + ml];
          unsigned hi = lds[c1 * 256 + (((msw ^ (c1 & 7) ^ (ch & 7)) << 3)) + ml];
          w[jj] = lo | (hi << 16);
        }
        uint4 v = make_uint4(w[0], w[1], w[2], w[3]);
        *(uint4*)&Cd[(mBase + m) * 12288 + cBase + hc * 192 + ch * 8] = v;
      }
    }
  }
#undef GL_A
#undef GL_B
#undef LDA
#undef LDB
#undef MFMA_Q
}

// ---------------- K7: out[b,o,n,s] = bias[n,o] + sum_{k,i} Gk[n,(b,i,s)]*W[n,k,i,o] ----------------
// bf16 LDS (25.6KB, 800B/row pad -> 2-way bank alias = free), uint4 16B staging
// loads, in-loop bf16 unpack. ~30KB LDS -> 5 blocks/CU.
__global__ __launch_bounds__(256, 4) void k_final(const u16* __restrict__ G0,
                                                  const u16* __restrict__ G1,
                                                  const u16* __restrict__ G2,
                                                  const float* __restrict__ W,
                                                  const float* __restrict__ biasN,
                                                  float* __restrict__ out){
  __shared__ __align__(16) u16 gs[32 * 400];   // per-b row: 384 bf16 + 16 pad
  __shared__ __align__(16) float ws4[1024];    // W[n][k] slice [i=32][o=32]
  __shared__ float bbuf[32];
  int bid = blockIdx.x;
  int n = (bid & 7) * 256 + (bid >> 3);   // XCD-swizzle: adjacent n share an XCD L2
  int t = threadIdx.x;
  int b = t >> 3, oc = t & 7;
  f32x4 acc[4][3];                         // [jo: o=oc+8*jo][s-quad]
  #pragma unroll
  for (int jo = 0; jo < 4; jo++)
    #pragma unroll
    for (int v = 0; v < 3; v++) acc[jo][v] = (f32x4){0.f, 0.f, 0.f, 0.f};

  const u16* srcs[3] = {G0, G1, G2};
  for (int k = 0; k < 3; k++){
    __syncthreads();
    // stage G[n] slab: 12288 bf16 = 1536 x 16B chunks; 48 chunks per b-row
    const uint4* src = (const uint4*)(srcs[k] + (long)n * 12288);
    #pragma unroll
    for (int p = 0; p < 6; p++){
      int c = t + p * 256;
      int br = c / 48, wi = c - br * 48;
      *(uint4*)&gs[br * 400 + wi * 8] = src[c];
    }
    const float4* wsrc = (const float4*)(W + (long)n * 3072 + k * 1024);
    *(float4*)&ws4[t * 4] = wsrc[t];
    if (k == 0 && t < 8) *(float4*)&bbuf[t * 4] = ((const float4*)(biasN + (long)n * 32))[t];
    __syncthreads();

    const u16* gp = gs + b * 400;
    #pragma unroll 4
    for (int ii = 0; ii < 16; ii++){       // two i per iter: i0=2ii, i1=2ii+1
      uint4 A  = *(const uint4*)&gp[ii * 24];
      uint4 Bc = *(const uint4*)&gp[ii * 24 + 8];
      uint4 Cc = *(const uint4*)&gp[ii * 24 + 16];
      float2 p0 = unp2(A.x),  p1 = unp2(A.y),  p2 = unp2(A.z),  p3 = unp2(A.w);
      float2 p4 = unp2(Bc.x), p5 = unp2(Bc.y), p6 = unp2(Bc.z), p7 = unp2(Bc.w);
      float2 p8 = unp2(Cc.x), p9 = unp2(Cc.y), pa = unp2(Cc.z), pb = unp2(Cc.w);
      f32x4 G0v0 = (f32x4){p0.x, p0.y, p1.x, p1.y};
      f32x4 G0v1 = (f32x4){p2.x, p2.y, p3.x, p3.y};
      f32x4 G0v2 = (f32x4){p4.x, p4.y, p5.x, p5.y};
      f32x4 G1v0 = (f32x4){p6.x, p6.y, p7.x, p7.y};
      f32x4 G1v1 = (f32x4){p8.x, p8.y, p9.x, p9.y};
      f32x4 G1v2 = (f32x4){pa.x, pa.y, pb.x, pb.y};
      #pragma unroll
      for (int jo = 0; jo < 4; jo++){
        float w0 = ws4[(ii * 2)     * 32 + oc + jo * 8];   // broadcast reads
        float w1 = ws4[(ii * 2 + 1) * 32 + oc + jo * 8];
        acc[jo][0] += G0v0 * w0;
        acc[jo][1] += G0v1 * w0;
        acc[jo][2] += G0v2 * w0;
        acc[jo][0] += G1v0 * w1;
        acc[jo][1] += G1v1 * w1;
        acc[jo][2] += G1v2 * w1;
      }
    }
  }
  #pragma unroll
  for (int jo = 0; jo < 4; jo++){
    int o = oc + jo * 8;
    float bv = bbuf[o];
    f32x4 bs = {bv, bv, bv, bv};
    long base = ((long)(b * 32 + o) * 2048 + n) * 12;
    *(f32x4*)(out + base)     = acc[jo][0] + bs;
    *(f32x4*)(out + base + 4) = acc[jo][1] + bs;
    *(f32x4*)(out + base + 8) = acc[jo][2] + bs;
  }
}

extern "C" void kernel_launch(void* const* d_in, const int* in_sizes, int n_in,
                              void* d_out, int out_size, void* d_ws, size_t ws_size,
                              hipStream_t stream){
  const float* x    = (const float*)d_in[0];
  const float* E1   = (const float*)d_in[1];
  const float* E2   = (const float*)d_in[2];
  const float* P1   = (const float*)d_in[3];
  const float* P2   = (const float*)d_in[4];
  const float* BP1  = (const float*)d_in[5];
  const float* BP2  = (const float*)d_in[6];
  const float* fc0w = (const float*)d_in[7];
  const float* fc0b = (const float*)d_in[8];
  const float* fc1w = (const float*)d_in[9];
  const float* fc1b = (const float*)d_in[10];
  const float* fc2w = (const float*)d_in[11];
  const float* fc2b = (const float*)d_in[12];
  float* out = (float*)d_out;

  char* ws = (char*)d_ws;
  size_t off = 0;
  auto carve = [&](size_t bytes) -> char* {
    char* p = ws + off;
    off += (bytes + 255) & ~(size_t)255;
    return p;
  };
  float* h1            = (float*)carve((size_t)65536 * 4);
  float* h2raw         = (float*)carve((size_t)512 * 4);
  float* mmat          = (float*)carve((size_t)256 * 4);
  u16* sup             = (u16*)carve((size_t)2048 * 2048 * 2);
  u16* Xbt             = (u16*)carve((size_t)12288 * 2048 * 2);
  u16* Xb              = (u16*)carve((size_t)2048 * 12288 * 2);
  u16* G1t             = (u16*)carve((size_t)12288 * 2048 * 2);
  u16* G1              = (u16*)carve((size_t)2048 * 12288 * 2);
  float* W             = (float*)carve((size_t)2048 * 3072 * 4);
  float* biasN         = (float*)carve((size_t)2048 * 32 * 4);
  u16* G2              = Xbt;   // alias: Xbt dead after GEMM1, GEMM2 writes G2 here
  (void)ws_size; (void)in_sizes; (void)n_in; (void)out_size;

  k_h1     <<<256, 256, 0, stream>>>(x, fc0w, fc0b, h1);
  k_h2a    <<<512, 256, 0, stream>>>(h1, fc1w, h2raw);
  k_h2b    <<<1, 512, 0, stream>>>(h2raw, fc1b, fc2w, fc2b, mmat);
  k_support<<<2048, 256, 0, stream>>>(E1, E2, mmat, sup);
  k_xbt2   <<<dim3(192, 32), 256, 0, stream>>>(x, Xb, Xbt);
  k_wb2    <<<6400, 256, 0, stream>>>(E1, E2, P1, P2, BP1, BP2, W, biasN);
  k_gemm   <<<dim3(32, 8), 512, 0, stream>>>(sup, Xbt, G1, G1t, 1);   // G1 = S@X
  k_gemm   <<<dim3(32, 8), 512, 0, stream>>>(sup, G1t, G2, G1t, 0);   // G2 = S@G1
  k_final  <<<2048, 256, 0, stream>>>(Xb, G1, G2, W, biasN, out);
}

// Round 6
// 580.932 us; speedup vs baseline: 1.8376x; 1.8376x over previous
//
#include <hip/hip_runtime.h>

// DGCN decomposition:
//   m = MLP(x[0])                       (tiny, fp32)
//   S = softmax(relu(E1 @ m @ E2^T))    (row softmax, fp32 -> bf16)
//   G1 = S @ X, G2 = S @ G1             (bf16 MFMA GEMMs, X = x as [m, (b,i,s)])
//   out[b,o,n,s] = bias[n,o] + sum_{k,i} Gk[n,(b,i,s)] * W[n,k,i,o]
// S^2 is never materialized (saves a 2048^3 GEMM).
//
// R8 (resubmit; R5 slot hit GPUAcquisitionTimeout, kernel never measured):
//   R7's 256x384 spilled acc to scratch (192 acc VGPRs > budget; WRITE_SIZE
//   623MB was spill traffic). New geometry: 128x384 tile, 8 waves, acc=96 regs,
//   grid 16x32 = 512 blocks = EXACTLY 2 residency rounds (zero tail). 3 phases
//   per K-tile (16 MFMA each), interleaved wave c-mapping so n-phase j uses B
//   regions {2j,2j+1}; counted gates vmcnt(4)/vmcnt(6)/vmcnt(6); staging
//   staggered 4/2/2 per phase. LDS 128 KiB. Epilogue single-pass (96 KB tile).

typedef float  f32x4  __attribute__((ext_vector_type(4)));
typedef __bf16 bf16x8 __attribute__((ext_vector_type(8)));
typedef unsigned short u16;

#define GLOAD16(gp, lp) __builtin_amdgcn_global_load_lds( \
    (const __attribute__((address_space(1))) void*)(gp),  \
    (__attribute__((address_space(3))) void*)(lp), 16, 0, 0)

__device__ __forceinline__ u16 f2bf(float f){
  union { float f; unsigned u; } v; v.f = f;
  unsigned u = v.u;
  u += 0x7fffu + ((u >> 16) & 1u);   // round-to-nearest-even
  return (u16)(u >> 16);
}
__device__ __forceinline__ float bf2f(u16 h){
  union { unsigned u; float f; } v; v.u = ((unsigned)h) << 16;
  return v.f;
}
// unpack one uint (2 packed bf16) -> float2 {lo, hi} (lo = lower address)
__device__ __forceinline__ float2 unp2(unsigned u){
  union { unsigned q; float f; } a, b;
  a.q = u << 16; b.q = u & 0xffff0000u;
  return make_float2(a.f, b.f);
}

// ---------------- K1: h1[i,n] = tanh(x[0,i,n,:] . fc0_w + fc0_b) ----------------
__global__ void k_h1(const float* __restrict__ x, const float* __restrict__ fc0w,
                     const float* __restrict__ fc0b, float* __restrict__ h1){
  int g = blockIdx.x * 256 + threadIdx.x;        // g = i*2048 + n, 65536 total
  const float* xp = x + (long)g * 12;
  float s = fc0b[0];
  #pragma unroll
  for (int j = 0; j < 12; j++) s += xp[j] * fc0w[j];
  h1[g] = tanhf(s);
}

// ---------------- K2a: h2raw[i*16+d] = sum_n h1[i,n]*fc1_w[d,n] ----------------
__global__ __launch_bounds__(256) void k_h2a(const float* __restrict__ h1,
                                             const float* __restrict__ fc1w,
                                             float* __restrict__ h2raw){
  __shared__ float red[4];
  int id = blockIdx.x;                 // 0..511 = i*16+d
  int i = id >> 4, d = id & 15;
  int t = threadIdx.x;
  const float* hp = h1 + i * 2048;
  const float* wp = fc1w + d * 2048;
  float s = 0.f;
  for (int nn = t; nn < 2048; nn += 256) s += hp[nn] * wp[nn];
  for (int off = 32; off > 0; off >>= 1) s += __shfl_down(s, off, 64);
  if ((t & 63) == 0) red[t >> 6] = s;
  __syncthreads();
  if (t == 0) h2raw[id] = red[0] + red[1] + red[2] + red[3];
}

// ---------------- K2b: h2 = tanh(h2raw + fc1_b); m[d,e] = tanh(sum_i h2[i,d]*fc2_w[e,i] + fc2_b[e]) ----------------
__global__ void k_h2b(const float* __restrict__ h2raw, const float* __restrict__ fc1b,
                      const float* __restrict__ fc2w, const float* __restrict__ fc2b,
                      float* __restrict__ mmat){
  __shared__ float h2[512];
  int t = threadIdx.x;                 // 512 threads
  {
    int d = t & 15;
    h2[t] = tanhf(h2raw[t] + fc1b[d]);
  }
  __syncthreads();
  if (t < 256){
    int dd = t >> 4, e = t & 15;
    float s2 = fc2b[e];
    #pragma unroll
    for (int ii = 0; ii < 32; ii++) s2 += h2[ii * 16 + dd] * fc2w[e * 32 + ii];
    mmat[dd * 16 + e] = tanhf(s2);
  }
}

// ---------------- K3: support row n = softmax_j(relu(sum_d' (E1[n]@m)[d'] * E2[j,d'])) -> bf16 ----------------
__global__ __launch_bounds__(256) void k_support(const float* __restrict__ E1,
                                                 const float* __restrict__ E2,
                                                 const float* __restrict__ mmat,
                                                 u16* __restrict__ sup){
  __shared__ float ml[256];
  __shared__ float tv[16];
  __shared__ float red[8];
  int n = blockIdx.x, t = threadIdx.x;
  ml[t] = mmat[t];
  __syncthreads();
  if (t < 16){
    float s = 0.f;
    const float* er = E1 + n * 16;
    #pragma unroll
    for (int d = 0; d < 16; d++) s += er[d] * ml[d * 16 + t];
    tv[t] = s;
  }
  __syncthreads();
  float lmax = -1e30f;
  float lv[8];
  #pragma unroll
  for (int p = 0; p < 8; p++){
    int j = t + p * 256;
    const float* e2 = E2 + j * 16;
    float s = 0.f;
    #pragma unroll
    for (int d = 0; d < 16; d++) s += tv[d] * e2[d];
    s = fmaxf(s, 0.f);                 // relu BEFORE softmax
    lv[p] = s;
    lmax = fmaxf(lmax, s);
  }
  for (int off = 32; off > 0; off >>= 1) lmax = fmaxf(lmax, __shfl_down(lmax, off, 64));
  if ((t & 63) == 0) red[t >> 6] = lmax;
  __syncthreads();
  if (t == 0) red[0] = fmaxf(fmaxf(red[0], red[1]), fmaxf(red[2], red[3]));
  __syncthreads();
  float mx = red[0];
  float lsum = 0.f;
  #pragma unroll
  for (int p = 0; p < 8; p++){ float e = __expf(lv[p] - mx); lv[p] = e; lsum += e; }
  for (int off = 32; off > 0; off >>= 1) lsum += __shfl_down(lsum, off, 64);
  if ((t & 63) == 0) red[4 + (t >> 6)] = lsum;
  __syncthreads();
  if (t == 0) red[4] = red[4] + red[5] + red[6] + red[7];
  __syncthreads();
  float inv = 1.f / red[4];
  #pragma unroll
  for (int p = 0; p < 8; p++) sup[(long)n * 2048 + t + p * 256] = f2bf(lv[p] * inv);
}

// ---------------- K4: fused Xb[m][c]=bf16(x), Xbt[c][m]=Xb[m][c] (reads x once) ----------------
__global__ __launch_bounds__(256) void k_xbt2(const float* __restrict__ x,
                                              u16* __restrict__ Xb,
                                              u16* __restrict__ Xbt){
  __shared__ u16 tile[64][65];
  int cT = blockIdx.x * 64;            // 192 tiles over 12288
  int mT = blockIdx.y * 64;            // 32 tiles over 2048
  int t = threadIdx.x;
  int r = t >> 6, cc = t & 63;
  int cg = cT + cc;
  int bi = cg / 12, s = cg - bi * 12;
  long xoff = (long)bi * 24576 + s;    // x[((bi)*2048 + m)*12 + s]
  #pragma unroll
  for (int p = 0; p < 16; p++){
    int rr = p * 4 + r;
    u16 v = f2bf(x[xoff + (long)(mT + rr) * 12]);
    tile[rr][cc] = v;
    Xb[(long)(mT + rr) * 12288 + cg] = v;
  }
  __syncthreads();
  #pragma unroll
  for (int p = 0; p < 16; p++){
    int rr = p * 4 + r;
    Xbt[(long)(cT + rr) * 2048 + mT + cc] = tile[cc][rr];
  }
}

// ---------------- K6: W[n,k,i,o] via float4 + L1 reuse (4 n per block share P slice) ----------------
__global__ __launch_bounds__(256) void k_wb2(const float* __restrict__ E1, const float* __restrict__ E2,
                                             const float* __restrict__ P1, const float* __restrict__ P2,
                                             const float* __restrict__ BP1, const float* __restrict__ BP2,
                                             float* __restrict__ W, float* __restrict__ biasN){
  int bid = blockIdx.x, t = threadIdx.x;
  if (bid < 6144){
    int nb = bid & 511, rb = bid >> 9;       // 512 n-blocks x 12 r-blocks
    int n = nb * 4 + (t >> 6);
    int r4 = rb * 64 + (t & 63);             // float4 index within 768
    const float* e1 = E1 + n * 16;
    const float* e2 = E2 + n * 16;
    f32x4 s = {0.f, 0.f, 0.f, 0.f};
    #pragma unroll
    for (int d = 0; d < 16; d++){
      f32x4 p1 = *(const f32x4*)(P1 + d * 3072 + r4 * 4);
      f32x4 p2 = *(const f32x4*)(P2 + d * 3072 + r4 * 4);
      s += p1 * e1[d] + p2 * e2[d];
    }
    *(f32x4*)(W + (long)n * 3072 + r4 * 4) = s;
  } else {
    int e = (bid - 6144) * 256 + t;          // 65536 bias outputs
    int n = e >> 5, o = e & 31;
    const float* e1 = E1 + n * 16;
    const float* e2 = E2 + n * 16;
    float s = 0.f;
    #pragma unroll
    for (int d = 0; d < 16; d++) s += e1[d] * BP1[d * 32 + o] + e2[d] * BP2[d * 32 + o];
    biasN[e] = s;
  }
}

// ---------------- GEMM: C[m][c] = sum_k A[m][k] * Bt[c][k]; 128x384 tile, 8 waves ----------------
// 512 blocks = exactly 2 residency rounds (128 KiB LDS, 1 block/CU), zero tail.
// Wave grid 2(m) x 4(n); wave c-columns INTERLEAVED: lc = nq2*128 + wn*32 +
// u2*16 + l15, so n-phase j consumes exactly B regions {2j,2j+1}. 3 phases per
// K-tile (BK=64): P0 = all A-frags + B(n0) + issue {A',B01'}, P1 = B(n1) +
// issue B23', P2 = B(n2) + issue B45'. Counted gates vmcnt(4)/6/6 (never 0).
// acc[4][6] = 96 VGPRs (fits; R7's 192 spilled). T2 swizzle via pre-swizzled
// global source; T5 setprio; T1 XCD swizzle. Epilogue: swizzled transposed
// C-tile (96 KB) in LDS, coalesced Ct rows + Cd column-gather.
__global__ __launch_bounds__(512, 2) void k_gemm(const u16* __restrict__ A,
                                                 const u16* __restrict__ Bt,
                                                 u16* __restrict__ Cd,
                                                 u16* __restrict__ Ct,
                                                 int writeT){
  // per buffer (u16): A [0,8192) = 128x64, B [8192,32768) = 384x64; buf1 +32768
  __shared__ u16 lds[65536];
  int tid  = threadIdx.x;
  int wave = tid >> 6, lane = tid & 63;
  int l15 = lane & 15, q = lane >> 4, l7 = l15 & 7;
  int wm = wave >> 2, wn = wave & 3;   // 2 x 4 waves; wave-tile 64(m) x 96(c, interleaved)

  // bijective XCD swizzle: lin 0..511; 4 consecutive slots per xcd share yN
  int lin  = blockIdx.y * 32 + blockIdx.x;   // 0..511
  int xcd  = lin & 7;
  int slot = lin >> 3;                 // 0..63
  int yN   = slot >> 2;                // 0..15  (m-tile)
  int xN   = (slot & 3) * 8 + xcd;     // 0..31  (c-tile)
  long mBase = (long)yN * 128;
  long cBase = (long)xN * 384;

  f32x4 acc[4][6];
  #pragma unroll
  for (int t2 = 0; t2 < 4; t2++)
    #pragma unroll
    for (int u2 = 0; u2 < 6; u2++) acc[t2][u2] = (f32x4){0.f, 0.f, 0.f, 0.f};

  // staging: per region (64 rows x 64 cols), chunk L = tid -> row = L>>3,
  // c_lds = L&7; source chunk pre-swizzled: cel = (tid&7) ^ ((tid>>3)&7)
  int Lrow = tid >> 3;
  int cel  = (tid & 7) ^ (Lrow & 7);
  const u16* gAp = A  + (mBase + Lrow) * 2048 + cel * 8;
  const u16* gBp = Bt + (cBase + Lrow) * 2048 + cel * 8;

  // A region r in {0,1}: lds[nx + r*4096]; B region r in {0..5}: lds[nx + 8192 + r*4096]
#define GL_A(nx, ko, r) GLOAD16(gAp + (r) * (64 * 2048) + (ko), \
                                lds + (nx) + (r) * 4096 + wave * 512)
#define GL_B(nx, ko, r) GLOAD16(gBp + (r) * (64 * 2048) + (ko), \
                                lds + (nx) + 8192 + (r) * 4096 + wave * 512)

  // all 4 A-frag rows for this wave (rows wm*64 .. wm*64+63)
#define LDA(dst) do { \
    _Pragma("unroll") \
    for (int t2 = 0; t2 < 4; t2++){ \
      int row = wm * 64 + t2 * 16 + l15; \
      _Pragma("unroll") \
      for (int kk = 0; kk < 2; kk++) \
        dst[t2][kk] = *(const bf16x8*)&lds[bA + row * 64 + (((kk << 2) | q) ^ l7) * 8]; \
    } } while(0)

  // B pair for n-third nq2: c-local rows nq2*128 + wn*32 + u2*16 + l15
#define LDB(dst, nq2) do { \
    _Pragma("unroll") \
    for (int u2 = 0; u2 < 2; u2++){ \
      int row = (nq2) * 128 + wn * 32 + u2 * 16 + l15; \
      _Pragma("unroll") \
      for (int kk = 0; kk < 2; kk++) \
        dst[u2][kk] = *(const bf16x8*)&lds[bB + row * 64 + (((kk << 2) | q) ^ l7) * 8]; \
    } } while(0)

#define MFMA_Q(AF, BB, nb) do { \
    __builtin_amdgcn_s_setprio(1); \
    _Pragma("unroll") \
    for (int t2 = 0; t2 < 4; t2++) \
      _Pragma("unroll") \
      for (int u2 = 0; u2 < 2; u2++) \
        _Pragma("unroll") \
        for (int kk = 0; kk < 2; kk++) \
          acc[t2][(nb) + u2] = __builtin_amdgcn_mfma_f32_16x16x32_bf16( \
              AF[t2][kk], BB[u2][kk], acc[t2][(nb) + u2], 0, 0, 0); \
    __builtin_amdgcn_s_setprio(0); \
  } while(0)

  // prologue: stage tile 0 in first-need order: A0,A1,B0,B1 | B2,B3 | B4,B5
  GL_A(0, 0, 0); GL_A(0, 0, 1); GL_B(0, 0, 0); GL_B(0, 0, 1);
  GL_B(0, 0, 2); GL_B(0, 0, 3);
  GL_B(0, 0, 4); GL_B(0, 0, 5);

  for (int t = 0; t < 32; t++){
    const int bufo = (t & 1) ? 32768 : 0;
    const int bA = bufo;
    const int bB = bufo + 8192;
    const int nx = 32768 - bufo;
    const long ko = (long)((t + 1) & 31) * 64;   // t=31 wraps (dummy stage)
    bf16x8 aA[4][2], bb[2][2];
    // ---- P0: gate vmcnt(4) (retire A,B0,B1; leave B23,B45 in flight) ----
    asm volatile("s_waitcnt vmcnt(4)" ::: "memory");
    __builtin_amdgcn_s_barrier();
    LDA(aA);
    LDB(bb, 0);
    GL_A(nx, ko, 0); GL_A(nx, ko, 1); GL_B(nx, ko, 0); GL_B(nx, ko, 1);
    __builtin_amdgcn_s_barrier();
    MFMA_Q(aA, bb, 0);
    // ---- P1: gate vmcnt(6) (retire B2,B3; leave B45 + 4 new) ----
    asm volatile("s_waitcnt vmcnt(6)" ::: "memory");
    __builtin_amdgcn_s_barrier();
    LDB(bb, 1);
    GL_B(nx, ko, 2); GL_B(nx, ko, 3);
    __builtin_amdgcn_s_barrier();
    MFMA_Q(aA, bb, 2);
    // ---- P2: gate vmcnt(6) (retire B4,B5; leave 6 new) ----
    asm volatile("s_waitcnt vmcnt(6)" ::: "memory");
    __builtin_amdgcn_s_barrier();
    LDB(bb, 2);
    GL_B(nx, ko, 4); GL_B(nx, ko, 5);
    __builtin_amdgcn_s_barrier();
    MFMA_Q(aA, bb, 4);
  }
  // drain the wrapped dummy prefetch before reusing LDS for the epilogue
  asm volatile("s_waitcnt vmcnt(0)" ::: "memory");
  __builtin_amdgcn_sched_barrier(0);
  __syncthreads();

  // ---- epilogue: transposed tile tileT[c][m] in LDS (swizzled), single pass ----
  // row lc (384), 128 m = 16 chunks of 8; chunk'(m,lc) = (m>>3) ^ (lc&7) ^ ((lc>>3)&7)
  // elem off = lc*128 + chunk'*8 + (m&7)
  #pragma unroll
  for (int t2 = 0; t2 < 4; t2++){
    int m0 = wm * 64 + t2 * 16 + q * 4;
    #pragma unroll
    for (int j = 0; j < 6; j++){
      int lc = (j >> 1) * 128 + wn * 32 + (j & 1) * 16 + l15;
      ushort4 v = make_ushort4(f2bf(acc[t2][j][0]), f2bf(acc[t2][j][1]),
                               f2bf(acc[t2][j][2]), f2bf(acc[t2][j][3]));
      int sw = ((m0 >> 3) ^ (lc & 7) ^ ((lc >> 3) & 7));
      *(ushort4*)&lds[lc * 128 + (sw << 3) + (m0 & 7)] = v;
    }
  }
  __syncthreads();
  if (writeT){
    // Ct rows are c: 12 passes x 32 rows; 16 lanes x 16B = 256B coalesced per row
    int rr0 = tid >> 4;       // 0..31
    int ch  = tid & 15;       // m-chunk 0..15
    #pragma unroll
    for (int p = 0; p < 12; p++){
      int r = p * 32 + rr0;
      int sw = (ch ^ (r & 7) ^ ((r >> 3) & 7));
      uint4 v = *(const uint4*)&lds[r * 128 + (sw << 3)];
      *(uint4*)&Ct[(cBase + r) * 2048 + mBase + ch * 8] = v;
    }
  }
  {
    // Cd rows are m: gather 8 c-column values per 16B chunk; 48 c-chunks/row
    int rr = tid >> 5;        // 0..15
    int ch = tid & 31;        // c-chunk
    #pragma unroll
    for (int p = 0; p < 8; p++){
      int m = p * 16 + rr;
      int msw = (m >> 3), ml = m & 7;
      #pragma unroll
      for (int half = 0; half < 2; half++){
        int cc = half ? (ch + 32) : ch;
        if (half && ch >= 16) break;
        unsigned w[4];
        #pragma unroll
        for (int jj = 0; jj < 4; jj++){
          int c0 = cc * 8 + jj * 2, c1 = c0 + 1;
          unsigned lo = lds[c0 * 128 + (((msw ^ (c0 & 7) ^ ((c0 >> 3) & 7)) << 3)) + ml];
          unsigned hi = lds[c1 * 128 + (((msw ^ (c1 & 7) ^ ((c1 >> 3) & 7)) << 3)) + ml];
          w[jj] = lo | (hi << 16);
        }
        uint4 v = make_uint4(w[0], w[1], w[2], w[3]);
        *(uint4*)&Cd[(mBase + m) * 12288 + cBase + cc * 8] = v;
      }
    }
  }
#undef GL_A
#undef GL_B
#undef LDA
#undef LDB
#undef MFMA_Q
}

// ---------------- K7: out[b,o,n,s] = bias[n,o] + sum_{k,i} Gk[n,(b,i,s)]*W[n,k,i,o] ----------------
// bf16 LDS (25.6KB, 800B/row pad -> 2-way bank alias = free), uint4 16B staging
// loads, in-loop bf16 unpack. ~30KB LDS -> 5 blocks/CU.
__global__ __launch_bounds__(256, 4) void k_final(const u16* __restrict__ G0,
                                                  const u16* __restrict__ G1,
                                                  const u16* __restrict__ G2,
                                                  const float* __restrict__ W,
                                                  const float* __restrict__ biasN,
                                                  float* __restrict__ out){
  __shared__ __align__(16) u16 gs[32 * 400];   // per-b row: 384 bf16 + 16 pad
  __shared__ __align__(16) float ws4[1024];    // W[n][k] slice [i=32][o=32]
  __shared__ float bbuf[32];
  int bid = blockIdx.x;
  int n = (bid & 7) * 256 + (bid >> 3);   // XCD-swizzle: adjacent n share an XCD L2
  int t = threadIdx.x;
  int b = t >> 3, oc = t & 7;
  f32x4 acc[4][3];                         // [jo: o=oc+8*jo][s-quad]
  #pragma unroll
  for (int jo = 0; jo < 4; jo++)
    #pragma unroll
    for (int v = 0; v < 3; v++) acc[jo][v] = (f32x4){0.f, 0.f, 0.f, 0.f};

  const u16* srcs[3] = {G0, G1, G2};
  for (int k = 0; k < 3; k++){
    __syncthreads();
    // stage G[n] slab: 12288 bf16 = 1536 x 16B chunks; 48 chunks per b-row
    const uint4* src = (const uint4*)(srcs[k] + (long)n * 12288);
    #pragma unroll
    for (int p = 0; p < 6; p++){
      int c = t + p * 256;
      int br = c / 48, wi = c - br * 48;
      *(uint4*)&gs[br * 400 + wi * 8] = src[c];
    }
    const float4* wsrc = (const float4*)(W + (long)n * 3072 + k * 1024);
    *(float4*)&ws4[t * 4] = wsrc[t];
    if (k == 0 && t < 8) *(float4*)&bbuf[t * 4] = ((const float4*)(biasN + (long)n * 32))[t];
    __syncthreads();

    const u16* gp = gs + b * 400;
    #pragma unroll 4
    for (int ii = 0; ii < 16; ii++){       // two i per iter: i0=2ii, i1=2ii+1
      uint4 A  = *(const uint4*)&gp[ii * 24];
      uint4 Bc = *(const uint4*)&gp[ii * 24 + 8];
      uint4 Cc = *(const uint4*)&gp[ii * 24 + 16];
      float2 p0 = unp2(A.x),  p1 = unp2(A.y),  p2 = unp2(A.z),  p3 = unp2(A.w);
      float2 p4 = unp2(Bc.x), p5 = unp2(Bc.y), p6 = unp2(Bc.z), p7 = unp2(Bc.w);
      float2 p8 = unp2(Cc.x), p9 = unp2(Cc.y), pa = unp2(Cc.z), pb = unp2(Cc.w);
      f32x4 G0v0 = (f32x4){p0.x, p0.y, p1.x, p1.y};
      f32x4 G0v1 = (f32x4){p2.x, p2.y, p3.x, p3.y};
      f32x4 G0v2 = (f32x4){p4.x, p4.y, p5.x, p5.y};
      f32x4 G1v0 = (f32x4){p6.x, p6.y, p7.x, p7.y};
      f32x4 G1v1 = (f32x4){p8.x, p8.y, p9.x, p9.y};
      f32x4 G1v2 = (f32x4){pa.x, pa.y, pb.x, pb.y};
      #pragma unroll
      for (int jo = 0; jo < 4; jo++){
        float w0 = ws4[(ii * 2)     * 32 + oc + jo * 8];   // broadcast reads
        float w1 = ws4[(ii * 2 + 1) * 32 + oc + jo * 8];
        acc[jo][0] += G0v0 * w0;
        acc[jo][1] += G0v1 * w0;
        acc[jo][2] += G0v2 * w0;
        acc[jo][0] += G1v0 * w1;
        acc[jo][1] += G1v1 * w1;
        acc[jo][2] += G1v2 * w1;
      }
    }
  }
  #pragma unroll
  for (int jo = 0; jo < 4; jo++){
    int o = oc + jo * 8;
    float bv = bbuf[o];
    f32x4 bs = {bv, bv, bv, bv};
    long base = ((long)(b * 32 + o) * 2048 + n) * 12;
    *(f32x4*)(out + base)     = acc[jo][0] + bs;
    *(f32x4*)(out + base + 4) = acc[jo][1] + bs;
    *(f32x4*)(out + base + 8) = acc[jo][2] + bs;
  }
}

extern "C" void kernel_launch(void* const* d_in, const int* in_sizes, int n_in,
                              void* d_out, int out_size, void* d_ws, size_t ws_size,
                              hipStream_t stream){
  const float* x    = (const float*)d_in[0];
  const float* E1   = (const float*)d_in[1];
  const float* E2   = (const float*)d_in[2];
  const float* P1   = (const float*)d_in[3];
  const float* P2   = (const float*)d_in[4];
  const float* BP1  = (const float*)d_in[5];
  const float* BP2  = (const float*)d_in[6];
  const float* fc0w = (const float*)d_in[7];
  const float* fc0b = (const float*)d_in[8];
  const float* fc1w = (const float*)d_in[9];
  const float* fc1b = (const float*)d_in[10];
  const float* fc2w = (const float*)d_in[11];
  const float* fc2b = (const float*)d_in[12];
  float* out = (float*)d_out;

  char* ws = (char*)d_ws;
  size_t off = 0;
  auto carve = [&](size_t bytes) -> char* {
    char* p = ws + off;
    off += (bytes + 255) & ~(size_t)255;
    return p;
  };
  float* h1            = (float*)carve((size_t)65536 * 4);
  float* h2raw         = (float*)carve((size_t)512 * 4);
  float* mmat          = (float*)carve((size_t)256 * 4);
  u16* sup             = (u16*)carve((size_t)2048 * 2048 * 2);
  u16* Xbt             = (u16*)carve((size_t)12288 * 2048 * 2);
  u16* Xb              = (u16*)carve((size_t)2048 * 12288 * 2);
  u16* G1t             = (u16*)carve((size_t)12288 * 2048 * 2);
  u16* G1              = (u16*)carve((size_t)2048 * 12288 * 2);
  float* W             = (float*)carve((size_t)2048 * 3072 * 4);
  float* biasN         = (float*)carve((size_t)2048 * 32 * 4);
  u16* G2              = Xbt;   // alias: Xbt dead after GEMM1, GEMM2 writes G2 here
  (void)ws_size; (void)in_sizes; (void)n_in; (void)out_size;

  k_h1     <<<256, 256, 0, stream>>>(x, fc0w, fc0b, h1);
  k_h2a    <<<512, 256, 0, stream>>>(h1, fc1w, h2raw);
  k_h2b    <<<1, 512, 0, stream>>>(h2raw, fc1b, fc2w, fc2b, mmat);
  k_support<<<2048, 256, 0, stream>>>(E1, E2, mmat, sup);
  k_xbt2   <<<dim3(192, 32), 256, 0, stream>>>(x, Xb, Xbt);
  k_wb2    <<<6400, 256, 0, stream>>>(E1, E2, P1, P2, BP1, BP2, W, biasN);
  k_gemm   <<<dim3(32, 16), 512, 0, stream>>>(sup, Xbt, G1, G1t, 1);   // G1 = S@X
  k_gemm   <<<dim3(32, 16), 512, 0, stream>>>(sup, G1t, G2, G1t, 0);   // G2 = S@G1
  k_final  <<<2048, 256, 0, stream>>>(Xb, G1, G2, W, biasN, out);
}

// Round 7
// 579.436 us; speedup vs baseline: 1.8423x; 1.0026x over previous
//
#include <hip/hip_runtime.h>

// DGCN decomposition:
//   m = MLP(x[0])                       (tiny, fp32)
//   S = softmax(relu(E1 @ m @ E2^T))    (row softmax, fp32 -> bf16)
//   G1 = S @ X, G2 = S @ G1             (bf16 MFMA GEMMs, X = x as [m, (b,i,s)])
//   out[b,o,n,s] = bias[n,o] + sum_{k,i} Gk[n,(b,i,s)] * W[n,k,i,o]
// S^2 is never materialized (saves a 2048^3 GEMM).
//
// R9: k_gemm K-loop collapsed to ONE barrier + one vmcnt(0) gate per K-tile
//   (was 6 barriers + 3 gates). All 20 ds_reads issued up-front (whole buf[t]
//   is resident by tile start), compiler inserts fine-grained lgkmcnt before
//   each MFMA cluster; GLOAD issues for t+1 stay staggered between the three
//   16-MFMA clusters (R6's win). Geometry unchanged from R8: 128x384 tile,
//   512 blocks = exactly 2 residency rounds, acc[4][6]=96 regs, 128 KiB LDS.

typedef float  f32x4  __attribute__((ext_vector_type(4)));
typedef __bf16 bf16x8 __attribute__((ext_vector_type(8)));
typedef unsigned short u16;

#define GLOAD16(gp, lp) __builtin_amdgcn_global_load_lds( \
    (const __attribute__((address_space(1))) void*)(gp),  \
    (__attribute__((address_space(3))) void*)(lp), 16, 0, 0)

__device__ __forceinline__ u16 f2bf(float f){
  union { float f; unsigned u; } v; v.f = f;
  unsigned u = v.u;
  u += 0x7fffu + ((u >> 16) & 1u);   // round-to-nearest-even
  return (u16)(u >> 16);
}
__device__ __forceinline__ float bf2f(u16 h){
  union { unsigned u; float f; } v; v.u = ((unsigned)h) << 16;
  return v.f;
}
// unpack one uint (2 packed bf16) -> float2 {lo, hi} (lo = lower address)
__device__ __forceinline__ float2 unp2(unsigned u){
  union { unsigned q; float f; } a, b;
  a.q = u << 16; b.q = u & 0xffff0000u;
  return make_float2(a.f, b.f);
}

// ---------------- K1: h1[i,n] = tanh(x[0,i,n,:] . fc0_w + fc0_b) ----------------
__global__ void k_h1(const float* __restrict__ x, const float* __restrict__ fc0w,
                     const float* __restrict__ fc0b, float* __restrict__ h1){
  int g = blockIdx.x * 256 + threadIdx.x;        // g = i*2048 + n, 65536 total
  const float* xp = x + (long)g * 12;
  float s = fc0b[0];
  #pragma unroll
  for (int j = 0; j < 12; j++) s += xp[j] * fc0w[j];
  h1[g] = tanhf(s);
}

// ---------------- K2a: h2raw[i*16+d] = sum_n h1[i,n]*fc1_w[d,n] ----------------
__global__ __launch_bounds__(256) void k_h2a(const float* __restrict__ h1,
                                             const float* __restrict__ fc1w,
                                             float* __restrict__ h2raw){
  __shared__ float red[4];
  int id = blockIdx.x;                 // 0..511 = i*16+d
  int i = id >> 4, d = id & 15;
  int t = threadIdx.x;
  const float* hp = h1 + i * 2048;
  const float* wp = fc1w + d * 2048;
  float s = 0.f;
  for (int nn = t; nn < 2048; nn += 256) s += hp[nn] * wp[nn];
  for (int off = 32; off > 0; off >>= 1) s += __shfl_down(s, off, 64);
  if ((t & 63) == 0) red[t >> 6] = s;
  __syncthreads();
  if (t == 0) h2raw[id] = red[0] + red[1] + red[2] + red[3];
}

// ---------------- K2b: h2 = tanh(h2raw + fc1_b); m[d,e] = tanh(sum_i h2[i,d]*fc2_w[e,i] + fc2_b[e]) ----------------
__global__ void k_h2b(const float* __restrict__ h2raw, const float* __restrict__ fc1b,
                      const float* __restrict__ fc2w, const float* __restrict__ fc2b,
                      float* __restrict__ mmat){
  __shared__ float h2[512];
  int t = threadIdx.x;                 // 512 threads
  {
    int d = t & 15;
    h2[t] = tanhf(h2raw[t] + fc1b[d]);
  }
  __syncthreads();
  if (t < 256){
    int dd = t >> 4, e = t & 15;
    float s2 = fc2b[e];
    #pragma unroll
    for (int ii = 0; ii < 32; ii++) s2 += h2[ii * 16 + dd] * fc2w[e * 32 + ii];
    mmat[dd * 16 + e] = tanhf(s2);
  }
}

// ---------------- K3: support row n = softmax_j(relu(sum_d' (E1[n]@m)[d'] * E2[j,d'])) -> bf16 ----------------
__global__ __launch_bounds__(256) void k_support(const float* __restrict__ E1,
                                                 const float* __restrict__ E2,
                                                 const float* __restrict__ mmat,
                                                 u16* __restrict__ sup){
  __shared__ float ml[256];
  __shared__ float tv[16];
  __shared__ float red[8];
  int n = blockIdx.x, t = threadIdx.x;
  ml[t] = mmat[t];
  __syncthreads();
  if (t < 16){
    float s = 0.f;
    const float* er = E1 + n * 16;
    #pragma unroll
    for (int d = 0; d < 16; d++) s += er[d] * ml[d * 16 + t];
    tv[t] = s;
  }
  __syncthreads();
  float lmax = -1e30f;
  float lv[8];
  #pragma unroll
  for (int p = 0; p < 8; p++){
    int j = t + p * 256;
    const float* e2 = E2 + j * 16;
    float s = 0.f;
    #pragma unroll
    for (int d = 0; d < 16; d++) s += tv[d] * e2[d];
    s = fmaxf(s, 0.f);                 // relu BEFORE softmax
    lv[p] = s;
    lmax = fmaxf(lmax, s);
  }
  for (int off = 32; off > 0; off >>= 1) lmax = fmaxf(lmax, __shfl_down(lmax, off, 64));
  if ((t & 63) == 0) red[t >> 6] = lmax;
  __syncthreads();
  if (t == 0) red[0] = fmaxf(fmaxf(red[0], red[1]), fmaxf(red[2], red[3]));
  __syncthreads();
  float mx = red[0];
  float lsum = 0.f;
  #pragma unroll
  for (int p = 0; p < 8; p++){ float e = __expf(lv[p] - mx); lv[p] = e; lsum += e; }
  for (int off = 32; off > 0; off >>= 1) lsum += __shfl_down(lsum, off, 64);
  if ((t & 63) == 0) red[4 + (t >> 6)] = lsum;
  __syncthreads();
  if (t == 0) red[4] = red[4] + red[5] + red[6] + red[7];
  __syncthreads();
  float inv = 1.f / red[4];
  #pragma unroll
  for (int p = 0; p < 8; p++) sup[(long)n * 2048 + t + p * 256] = f2bf(lv[p] * inv);
}

// ---------------- K4: fused Xb[m][c]=bf16(x), Xbt[c][m]=Xb[m][c] (reads x once) ----------------
__global__ __launch_bounds__(256) void k_xbt2(const float* __restrict__ x,
                                              u16* __restrict__ Xb,
                                              u16* __restrict__ Xbt){
  __shared__ u16 tile[64][65];
  int cT = blockIdx.x * 64;            // 192 tiles over 12288
  int mT = blockIdx.y * 64;            // 32 tiles over 2048
  int t = threadIdx.x;
  int r = t >> 6, cc = t & 63;
  int cg = cT + cc;
  int bi = cg / 12, s = cg - bi * 12;
  long xoff = (long)bi * 24576 + s;    // x[((bi)*2048 + m)*12 + s]
  #pragma unroll
  for (int p = 0; p < 16; p++){
    int rr = p * 4 + r;
    u16 v = f2bf(x[xoff + (long)(mT + rr) * 12]);
    tile[rr][cc] = v;
    Xb[(long)(mT + rr) * 12288 + cg] = v;
  }
  __syncthreads();
  #pragma unroll
  for (int p = 0; p < 16; p++){
    int rr = p * 4 + r;
    Xbt[(long)(cT + rr) * 2048 + mT + cc] = tile[cc][rr];
  }
}

// ---------------- K6: W[n,k,i,o] via float4 + L1 reuse (4 n per block share P slice) ----------------
__global__ __launch_bounds__(256) void k_wb2(const float* __restrict__ E1, const float* __restrict__ E2,
                                             const float* __restrict__ P1, const float* __restrict__ P2,
                                             const float* __restrict__ BP1, const float* __restrict__ BP2,
                                             float* __restrict__ W, float* __restrict__ biasN){
  int bid = blockIdx.x, t = threadIdx.x;
  if (bid < 6144){
    int nb = bid & 511, rb = bid >> 9;       // 512 n-blocks x 12 r-blocks
    int n = nb * 4 + (t >> 6);
    int r4 = rb * 64 + (t & 63);             // float4 index within 768
    const float* e1 = E1 + n * 16;
    const float* e2 = E2 + n * 16;
    f32x4 s = {0.f, 0.f, 0.f, 0.f};
    #pragma unroll
    for (int d = 0; d < 16; d++){
      f32x4 p1 = *(const f32x4*)(P1 + d * 3072 + r4 * 4);
      f32x4 p2 = *(const f32x4*)(P2 + d * 3072 + r4 * 4);
      s += p1 * e1[d] + p2 * e2[d];
    }
    *(f32x4*)(W + (long)n * 3072 + r4 * 4) = s;
  } else {
    int e = (bid - 6144) * 256 + t;          // 65536 bias outputs
    int n = e >> 5, o = e & 31;
    const float* e1 = E1 + n * 16;
    const float* e2 = E2 + n * 16;
    float s = 0.f;
    #pragma unroll
    for (int d = 0; d < 16; d++) s += e1[d] * BP1[d * 32 + o] + e2[d] * BP2[d * 32 + o];
    biasN[e] = s;
  }
}

// ---------------- GEMM: C[m][c] = sum_k A[m][k] * Bt[c][k]; 128x384 tile, 8 waves ----------------
// 512 blocks = exactly 2 residency rounds (128 KiB LDS, 1 block/CU), zero tail.
// ONE barrier + one vmcnt(0) gate per K-tile: all of buf[t] was staged by tile
// t-1, so after the gate+barrier the whole tile is readable. 20 ds_reads issued
// up-front (compiler auto-inserts fine-grained lgkmcnt before each MFMA
// cluster); GLOADs for t+1 staggered between the three 16-MFMA clusters.
// Hazard: each wave's ds_reads are consumed by its MFMAs before the next
// barrier, so t+1's GLOADs (after that barrier) never overwrite live reads.
// acc[4][6]=96 regs + frags 40. T2 swizzle; T5 setprio; T1 XCD swizzle.
__global__ __launch_bounds__(512, 2) void k_gemm(const u16* __restrict__ A,
                                                 const u16* __restrict__ Bt,
                                                 u16* __restrict__ Cd,
                                                 u16* __restrict__ Ct,
                                                 int writeT){
  // per buffer (u16): A [0,8192) = 128x64, B [8192,32768) = 384x64; buf1 +32768
  __shared__ u16 lds[65536];
  int tid  = threadIdx.x;
  int wave = tid >> 6, lane = tid & 63;
  int l15 = lane & 15, q = lane >> 4, l7 = l15 & 7;
  int wm = wave >> 2, wn = wave & 3;   // 2 x 4 waves; wave-tile 64(m) x 96(c, interleaved)

  // bijective XCD swizzle: lin 0..511; 4 consecutive slots per xcd share yN
  int lin  = blockIdx.y * 32 + blockIdx.x;   // 0..511
  int xcd  = lin & 7;
  int slot = lin >> 3;                 // 0..63
  int yN   = slot >> 2;                // 0..15  (m-tile)
  int xN   = (slot & 3) * 8 + xcd;     // 0..31  (c-tile)
  long mBase = (long)yN * 128;
  long cBase = (long)xN * 384;

  f32x4 acc[4][6];
  #pragma unroll
  for (int t2 = 0; t2 < 4; t2++)
    #pragma unroll
    for (int u2 = 0; u2 < 6; u2++) acc[t2][u2] = (f32x4){0.f, 0.f, 0.f, 0.f};

  // staging: per region (64 rows x 64 cols), chunk L = tid -> row = L>>3,
  // c_lds = L&7; source chunk pre-swizzled: cel = (tid&7) ^ ((tid>>3)&7)
  int Lrow = tid >> 3;
  int cel  = (tid & 7) ^ (Lrow & 7);
  const u16* gAp = A  + (mBase + Lrow) * 2048 + cel * 8;
  const u16* gBp = Bt + (cBase + Lrow) * 2048 + cel * 8;

  // A region r in {0,1}: lds[nx + r*4096]; B region r in {0..5}: lds[nx + 8192 + r*4096]
#define GL_A(nx, ko, r) GLOAD16(gAp + (r) * (64 * 2048) + (ko), \
                                lds + (nx) + (r) * 4096 + wave * 512)
#define GL_B(nx, ko, r) GLOAD16(gBp + (r) * (64 * 2048) + (ko), \
                                lds + (nx) + 8192 + (r) * 4096 + wave * 512)

  // all 4 A-frag rows for this wave (rows wm*64 .. wm*64+63)
#define LDA(dst) do { \
    _Pragma("unroll") \
    for (int t2 = 0; t2 < 4; t2++){ \
      int row = wm * 64 + t2 * 16 + l15; \
      _Pragma("unroll") \
      for (int kk = 0; kk < 2; kk++) \
        dst[t2][kk] = *(const bf16x8*)&lds[bA + row * 64 + (((kk << 2) | q) ^ l7) * 8]; \
    } } while(0)

  // B pair for n-third nq2: c-local rows nq2*128 + wn*32 + u2*16 + l15
#define LDB(dst, nq2) do { \
    _Pragma("unroll") \
    for (int u2 = 0; u2 < 2; u2++){ \
      int row = (nq2) * 128 + wn * 32 + u2 * 16 + l15; \
      _Pragma("unroll") \
      for (int kk = 0; kk < 2; kk++) \
        dst[u2][kk] = *(const bf16x8*)&lds[bB + row * 64 + (((kk << 2) | q) ^ l7) * 8]; \
    } } while(0)

#define MFMA_Q(AF, BB, nb) do { \
    __builtin_amdgcn_s_setprio(1); \
    _Pragma("unroll") \
    for (int t2 = 0; t2 < 4; t2++) \
      _Pragma("unroll") \
      for (int u2 = 0; u2 < 2; u2++) \
        _Pragma("unroll") \
        for (int kk = 0; kk < 2; kk++) \
          acc[t2][(nb) + u2] = __builtin_amdgcn_mfma_f32_16x16x32_bf16( \
              AF[t2][kk], BB[u2][kk], acc[t2][(nb) + u2], 0, 0, 0); \
    __builtin_amdgcn_s_setprio(0); \
  } while(0)

  // prologue: stage tile 0 (staggered issue order)
  GL_A(0, 0, 0); GL_A(0, 0, 1); GL_B(0, 0, 0); GL_B(0, 0, 1);
  GL_B(0, 0, 2); GL_B(0, 0, 3);
  GL_B(0, 0, 4); GL_B(0, 0, 5);

  for (int t = 0; t < 32; t++){
    const int bufo = (t & 1) ? 32768 : 0;
    const int bA = bufo;
    const int bB = bufo + 8192;
    const int nx = 32768 - bufo;
    const long ko = (long)(t + 1) * 64;
    bf16x8 aA[4][2], bb0[2][2], bb1[2][2], bb2[2][2];
    // ---- gate: own 8 stages of buf[t] retired (had a full K-tile of slack);
    //      barrier makes every wave's stages visible to all ----
    asm volatile("s_waitcnt vmcnt(0)" ::: "memory");
    __builtin_amdgcn_s_barrier();
    // ---- all 20 ds_reads up-front; compiler emits fine-grained lgkmcnt ----
    LDA(aA);
    LDB(bb0, 0);
    LDB(bb1, 1);
    LDB(bb2, 2);
    // ---- cluster n0; stagger t+1 GLOAD issues between clusters ----
    if (t < 31){ GL_A(nx, ko, 0); GL_A(nx, ko, 1); GL_B(nx, ko, 0); GL_B(nx, ko, 1); }
    MFMA_Q(aA, bb0, 0);
    if (t < 31){ GL_B(nx, ko, 2); GL_B(nx, ko, 3); }
    MFMA_Q(aA, bb1, 2);
    if (t < 31){ GL_B(nx, ko, 4); GL_B(nx, ko, 5); }
    MFMA_Q(aA, bb2, 4);
    // single end-of-tile barrier is the next iteration's start barrier
  }
  // nothing outstanding (t=31 issued no GLOADs); belt-and-braces before LDS reuse
  asm volatile("s_waitcnt vmcnt(0)" ::: "memory");
  __builtin_amdgcn_sched_barrier(0);
  __syncthreads();

  // ---- epilogue: transposed tile tileT[c][m] in LDS (swizzled), single pass ----
  // row lc (384), 128 m = 16 chunks of 8; chunk'(m,lc) = (m>>3) ^ (lc&7) ^ ((lc>>3)&7)
  // elem off = lc*128 + chunk'*8 + (m&7)
  #pragma unroll
  for (int t2 = 0; t2 < 4; t2++){
    int m0 = wm * 64 + t2 * 16 + q * 4;
    #pragma unroll
    for (int j = 0; j < 6; j++){
      int lc = (j >> 1) * 128 + wn * 32 + (j & 1) * 16 + l15;
      ushort4 v = make_ushort4(f2bf(acc[t2][j][0]), f2bf(acc[t2][j][1]),
                               f2bf(acc[t2][j][2]), f2bf(acc[t2][j][3]));
      int sw = ((m0 >> 3) ^ (lc & 7) ^ ((lc >> 3) & 7));
      *(ushort4*)&lds[lc * 128 + (sw << 3) + (m0 & 7)] = v;
    }
  }
  __syncthreads();
  if (writeT){
    // Ct rows are c: 12 passes x 32 rows; 16 lanes x 16B = 256B coalesced per row
    int rr0 = tid >> 4;       // 0..31
    int ch  = tid & 15;       // m-chunk 0..15
    #pragma unroll
    for (int p = 0; p < 12; p++){
      int r = p * 32 + rr0;
      int sw = (ch ^ (r & 7) ^ ((r >> 3) & 7));
      uint4 v = *(const uint4*)&lds[r * 128 + (sw << 3)];
      *(uint4*)&Ct[(cBase + r) * 2048 + mBase + ch * 8] = v;
    }
  }
  {
    // Cd rows are m: gather 8 c-column values per 16B chunk; 48 c-chunks/row
    int rr = tid >> 5;        // 0..15
    int ch = tid & 31;        // c-chunk
    #pragma unroll
    for (int p = 0; p < 8; p++){
      int m = p * 16 + rr;
      int msw = (m >> 3), ml = m & 7;
      #pragma unroll
      for (int half = 0; half < 2; half++){
        int cc = half ? (ch + 32) : ch;
        if (half && ch >= 16) break;
        unsigned w[4];
        #pragma unroll
        for (int jj = 0; jj < 4; jj++){
          int c0 = cc * 8 + jj * 2, c1 = c0 + 1;
          unsigned lo = lds[c0 * 128 + (((msw ^ (c0 & 7) ^ ((c0 >> 3) & 7)) << 3)) + ml];
          unsigned hi = lds[c1 * 128 + (((msw ^ (c1 & 7) ^ ((c1 >> 3) & 7)) << 3)) + ml];
          w[jj] = lo | (hi << 16);
        }
        uint4 v = make_uint4(w[0], w[1], w[2], w[3]);
        *(uint4*)&Cd[(mBase + m) * 12288 + cBase + cc * 8] = v;
      }
    }
  }
#undef GL_A
#undef GL_B
#undef LDA
#undef LDB
#undef MFMA_Q
}

// ---------------- K7: out[b,o,n,s] = bias[n,o] + sum_{k,i} Gk[n,(b,i,s)]*W[n,k,i,o] ----------------
// bf16 LDS (25.6KB, 800B/row pad -> 2-way bank alias = free), uint4 16B staging
// loads, in-loop bf16 unpack. ~30KB LDS -> 5 blocks/CU.
__global__ __launch_bounds__(256, 4) void k_final(const u16* __restrict__ G0,
                                                  const u16* __restrict__ G1,
                                                  const u16* __restrict__ G2,
                                                  const float* __restrict__ W,
                                                  const float* __restrict__ biasN,
                                                  float* __restrict__ out){
  __shared__ __align__(16) u16 gs[32 * 400];   // per-b row: 384 bf16 + 16 pad
  __shared__ __align__(16) float ws4[1024];    // W[n][k] slice [i=32][o=32]
  __shared__ float bbuf[32];
  int bid = blockIdx.x;
  int n = (bid & 7) * 256 + (bid >> 3);   // XCD-swizzle: adjacent n share an XCD L2
  int t = threadIdx.x;
  int b = t >> 3, oc = t & 7;
  f32x4 acc[4][3];                         // [jo: o=oc+8*jo][s-quad]
  #pragma unroll
  for (int jo = 0; jo < 4; jo++)
    #pragma unroll
    for (int v = 0; v < 3; v++) acc[jo][v] = (f32x4){0.f, 0.f, 0.f, 0.f};

  const u16* srcs[3] = {G0, G1, G2};
  for (int k = 0; k < 3; k++){
    __syncthreads();
    // stage G[n] slab: 12288 bf16 = 1536 x 16B chunks; 48 chunks per b-row
    const uint4* src = (const uint4*)(srcs[k] + (long)n * 12288);
    #pragma unroll
    for (int p = 0; p < 6; p++){
      int c = t + p * 256;
      int br = c / 48, wi = c - br * 48;
      *(uint4*)&gs[br * 400 + wi * 8] = src[c];
    }
    const float4* wsrc = (const float4*)(W + (long)n * 3072 + k * 1024);
    *(float4*)&ws4[t * 4] = wsrc[t];
    if (k == 0 && t < 8) *(float4*)&bbuf[t * 4] = ((const float4*)(biasN + (long)n * 32))[t];
    __syncthreads();

    const u16* gp = gs + b * 400;
    #pragma unroll 4
    for (int ii = 0; ii < 16; ii++){       // two i per iter: i0=2ii, i1=2ii+1
      uint4 A  = *(const uint4*)&gp[ii * 24];
      uint4 Bc = *(const uint4*)&gp[ii * 24 + 8];
      uint4 Cc = *(const uint4*)&gp[ii * 24 + 16];
      float2 p0 = unp2(A.x),  p1 = unp2(A.y),  p2 = unp2(A.z),  p3 = unp2(A.w);
      float2 p4 = unp2(Bc.x), p5 = unp2(Bc.y), p6 = unp2(Bc.z), p7 = unp2(Bc.w);
      float2 p8 = unp2(Cc.x), p9 = unp2(Cc.y), pa = unp2(Cc.z), pb = unp2(Cc.w);
      f32x4 G0v0 = (f32x4){p0.x, p0.y, p1.x, p1.y};
      f32x4 G0v1 = (f32x4){p2.x, p2.y, p3.x, p3.y};
      f32x4 G0v2 = (f32x4){p4.x, p4.y, p5.x, p5.y};
      f32x4 G1v0 = (f32x4){p6.x, p6.y, p7.x, p7.y};
      f32x4 G1v1 = (f32x4){p8.x, p8.y, p9.x, p9.y};
      f32x4 G1v2 = (f32x4){pa.x, pa.y, pb.x, pb.y};
      #pragma unroll
      for (int jo = 0; jo < 4; jo++){
        float w0 = ws4[(ii * 2)     * 32 + oc + jo * 8];   // broadcast reads
        float w1 = ws4[(ii * 2 + 1) * 32 + oc + jo * 8];
        acc[jo][0] += G0v0 * w0;
        acc[jo][1] += G0v1 * w0;
        acc[jo][2] += G0v2 * w0;
        acc[jo][0] += G1v0 * w1;
        acc[jo][1] += G1v1 * w1;
        acc[jo][2] += G1v2 * w1;
      }
    }
  }
  #pragma unroll
  for (int jo = 0; jo < 4; jo++){
    int o = oc + jo * 8;
    float bv = bbuf[o];
    f32x4 bs = {bv, bv, bv, bv};
    long base = ((long)(b * 32 + o) * 2048 + n) * 12;
    *(f32x4*)(out + base)     = acc[jo][0] + bs;
    *(f32x4*)(out + base + 4) = acc[jo][1] + bs;
    *(f32x4*)(out + base + 8) = acc[jo][2] + bs;
  }
}

extern "C" void kernel_launch(void* const* d_in, const int* in_sizes, int n_in,
                              void* d_out, int out_size, void* d_ws, size_t ws_size,
                              hipStream_t stream){
  const float* x    = (const float*)d_in[0];
  const float* E1   = (const float*)d_in[1];
  const float* E2   = (const float*)d_in[2];
  const float* P1   = (const float*)d_in[3];
  const float* P2   = (const float*)d_in[4];
  const float* BP1  = (const float*)d_in[5];
  const float* BP2  = (const float*)d_in[6];
  const float* fc0w = (const float*)d_in[7];
  const float* fc0b = (const float*)d_in[8];
  const float* fc1w = (const float*)d_in[9];
  const float* fc1b = (const float*)d_in[10];
  const float* fc2w = (const float*)d_in[11];
  const float* fc2b = (const float*)d_in[12];
  float* out = (float*)d_out;

  char* ws = (char*)d_ws;
  size_t off = 0;
  auto carve = [&](size_t bytes) -> char* {
    char* p = ws + off;
    off += (bytes + 255) & ~(size_t)255;
    return p;
  };
  float* h1            = (float*)carve((size_t)65536 * 4);
  float* h2raw         = (float*)carve((size_t)512 * 4);
  float* mmat          = (float*)carve((size_t)256 * 4);
  u16* sup             = (u16*)carve((size_t)2048 * 2048 * 2);
  u16* Xbt             = (u16*)carve((size_t)12288 * 2048 * 2);
  u16* Xb              = (u16*)carve((size_t)2048 * 12288 * 2);
  u16* G1t             = (u16*)carve((size_t)12288 * 2048 * 2);
  u16* G1              = (u16*)carve((size_t)2048 * 12288 * 2);
  float* W             = (float*)carve((size_t)2048 * 3072 * 4);
  float* biasN         = (float*)carve((size_t)2048 * 32 * 4);
  u16* G2              = Xbt;   // alias: Xbt dead after GEMM1, GEMM2 writes G2 here
  (void)ws_size; (void)in_sizes; (void)n_in; (void)out_size;

  k_h1     <<<256, 256, 0, stream>>>(x, fc0w, fc0b, h1);
  k_h2a    <<<512, 256, 0, stream>>>(h1, fc1w, h2raw);
  k_h2b    <<<1, 512, 0, stream>>>(h2raw, fc1b, fc2w, fc2b, mmat);
  k_support<<<2048, 256, 0, stream>>>(E1, E2, mmat, sup);
  k_xbt2   <<<dim3(192, 32), 256, 0, stream>>>(x, Xb, Xbt);
  k_wb2    <<<6400, 256, 0, stream>>>(E1, E2, P1, P2, BP1, BP2, W, biasN);
  k_gemm   <<<dim3(32, 16), 512, 0, stream>>>(sup, Xbt, G1, G1t, 1);   // G1 = S@X
  k_gemm   <<<dim3(32, 16), 512, 0, stream>>>(sup, G1t, G2, G1t, 0);   // G2 = S@G1
  k_final  <<<2048, 256, 0, stream>>>(Xb, G1, G2, W, biasN, out);
}

// Round 8
// 557.373 us; speedup vs baseline: 1.9152x; 1.0396x over previous
//
#include <hip/hip_runtime.h>

// DGCN decomposition:
//   m = MLP(x[0])                       (tiny, fp32)
//   S = softmax(relu(E1 @ m @ E2^T))    (row softmax, fp32 -> bf16)
//   G1 = S @ X, G2 = S @ G1             (bf16 MFMA GEMMs, X = x as [m, (b,i,s)])
//   out[b,o,n,s] = bias[n,o] + sum_{k,i} Gk[n,(b,i,s)] * W[n,k,i,o]
// S^2 is never materialized (saves a 2048^3 GEMM).
//
// R10: 2 blocks/CU for cross-block overlap (m114/m97 mechanism): tile 128x192,
//   LDS 80 KiB (A 16K + B 24K per buffer, double-buffered), grid 16x64 = 1024
//   blocks = exactly 2 rounds at 2 blocks/CU, launch_bounds(512,4) caps VGPR
//   at 128 (acc now 48 regs). K-tile body unchanged from R9: one vmcnt(0) gate
//   + one barrier, 14 ds_reads up-front, 5 GLOADs staggered between the three
//   8-MFMA clusters. Two independent blocks per CU phase-shift so one block's
//   MFMA covers the other's gate/read window.

typedef float  f32x4  __attribute__((ext_vector_type(4)));
typedef __bf16 bf16x8 __attribute__((ext_vector_type(8)));
typedef unsigned short u16;

#define GLOAD16(gp, lp) __builtin_amdgcn_global_load_lds( \
    (const __attribute__((address_space(1))) void*)(gp),  \
    (__attribute__((address_space(3))) void*)(lp), 16, 0, 0)

__device__ __forceinline__ u16 f2bf(float f){
  union { float f; unsigned u; } v; v.f = f;
  unsigned u = v.u;
  u += 0x7fffu + ((u >> 16) & 1u);   // round-to-nearest-even
  return (u16)(u >> 16);
}
__device__ __forceinline__ float bf2f(u16 h){
  union { unsigned u; float f; } v; v.u = ((unsigned)h) << 16;
  return v.f;
}
// unpack one uint (2 packed bf16) -> float2 {lo, hi} (lo = lower address)
__device__ __forceinline__ float2 unp2(unsigned u){
  union { unsigned q; float f; } a, b;
  a.q = u << 16; b.q = u & 0xffff0000u;
  return make_float2(a.f, b.f);
}

// ---------------- K1: h1[i,n] = tanh(x[0,i,n,:] . fc0_w + fc0_b) ----------------
__global__ void k_h1(const float* __restrict__ x, const float* __restrict__ fc0w,
                     const float* __restrict__ fc0b, float* __restrict__ h1){
  int g = blockIdx.x * 256 + threadIdx.x;        // g = i*2048 + n, 65536 total
  const float* xp = x + (long)g * 12;
  float s = fc0b[0];
  #pragma unroll
  for (int j = 0; j < 12; j++) s += xp[j] * fc0w[j];
  h1[g] = tanhf(s);
}

// ---------------- K2a: h2raw[i*16+d] = sum_n h1[i,n]*fc1_w[d,n] ----------------
__global__ __launch_bounds__(256) void k_h2a(const float* __restrict__ h1,
                                             const float* __restrict__ fc1w,
                                             float* __restrict__ h2raw){
  __shared__ float red[4];
  int id = blockIdx.x;                 // 0..511 = i*16+d
  int i = id >> 4, d = id & 15;
  int t = threadIdx.x;
  const float* hp = h1 + i * 2048;
  const float* wp = fc1w + d * 2048;
  float s = 0.f;
  for (int nn = t; nn < 2048; nn += 256) s += hp[nn] * wp[nn];
  for (int off = 32; off > 0; off >>= 1) s += __shfl_down(s, off, 64);
  if ((t & 63) == 0) red[t >> 6] = s;
  __syncthreads();
  if (t == 0) h2raw[id] = red[0] + red[1] + red[2] + red[3];
}

// ---------------- K2b: h2 = tanh(h2raw + fc1_b); m[d,e] = tanh(sum_i h2[i,d]*fc2_w[e,i] + fc2_b[e]) ----------------
__global__ void k_h2b(const float* __restrict__ h2raw, const float* __restrict__ fc1b,
                      const float* __restrict__ fc2w, const float* __restrict__ fc2b,
                      float* __restrict__ mmat){
  __shared__ float h2[512];
  int t = threadIdx.x;                 // 512 threads
  {
    int d = t & 15;
    h2[t] = tanhf(h2raw[t] + fc1b[d]);
  }
  __syncthreads();
  if (t < 256){
    int dd = t >> 4, e = t & 15;
    float s2 = fc2b[e];
    #pragma unroll
    for (int ii = 0; ii < 32; ii++) s2 += h2[ii * 16 + dd] * fc2w[e * 32 + ii];
    mmat[dd * 16 + e] = tanhf(s2);
  }
}

// ---------------- K3: support row n = softmax_j(relu(sum_d' (E1[n]@m)[d'] * E2[j,d'])) -> bf16 ----------------
__global__ __launch_bounds__(256) void k_support(const float* __restrict__ E1,
                                                 const float* __restrict__ E2,
                                                 const float* __restrict__ mmat,
                                                 u16* __restrict__ sup){
  __shared__ float ml[256];
  __shared__ float tv[16];
  __shared__ float red[8];
  int n = blockIdx.x, t = threadIdx.x;
  ml[t] = mmat[t];
  __syncthreads();
  if (t < 16){
    float s = 0.f;
    const float* er = E1 + n * 16;
    #pragma unroll
    for (int d = 0; d < 16; d++) s += er[d] * ml[d * 16 + t];
    tv[t] = s;
  }
  __syncthreads();
  float lmax = -1e30f;
  float lv[8];
  #pragma unroll
  for (int p = 0; p < 8; p++){
    int j = t + p * 256;
    const float* e2 = E2 + j * 16;
    float s = 0.f;
    #pragma unroll
    for (int d = 0; d < 16; d++) s += tv[d] * e2[d];
    s = fmaxf(s, 0.f);                 // relu BEFORE softmax
    lv[p] = s;
    lmax = fmaxf(lmax, s);
  }
  for (int off = 32; off > 0; off >>= 1) lmax = fmaxf(lmax, __shfl_down(lmax, off, 64));
  if ((t & 63) == 0) red[t >> 6] = lmax;
  __syncthreads();
  if (t == 0) red[0] = fmaxf(fmaxf(red[0], red[1]), fmaxf(red[2], red[3]));
  __syncthreads();
  float mx = red[0];
  float lsum = 0.f;
  #pragma unroll
  for (int p = 0; p < 8; p++){ float e = __expf(lv[p] - mx); lv[p] = e; lsum += e; }
  for (int off = 32; off > 0; off >>= 1) lsum += __shfl_down(lsum, off, 64);
  if ((t & 63) == 0) red[4 + (t >> 6)] = lsum;
  __syncthreads();
  if (t == 0) red[4] = red[4] + red[5] + red[6] + red[7];
  __syncthreads();
  float inv = 1.f / red[4];
  #pragma unroll
  for (int p = 0; p < 8; p++) sup[(long)n * 2048 + t + p * 256] = f2bf(lv[p] * inv);
}

// ---------------- K4: fused Xb[m][c]=bf16(x), Xbt[c][m]=Xb[m][c] (reads x once) ----------------
__global__ __launch_bounds__(256) void k_xbt2(const float* __restrict__ x,
                                              u16* __restrict__ Xb,
                                              u16* __restrict__ Xbt){
  __shared__ u16 tile[64][65];
  int cT = blockIdx.x * 64;            // 192 tiles over 12288
  int mT = blockIdx.y * 64;            // 32 tiles over 2048
  int t = threadIdx.x;
  int r = t >> 6, cc = t & 63;
  int cg = cT + cc;
  int bi = cg / 12, s = cg - bi * 12;
  long xoff = (long)bi * 24576 + s;    // x[((bi)*2048 + m)*12 + s]
  #pragma unroll
  for (int p = 0; p < 16; p++){
    int rr = p * 4 + r;
    u16 v = f2bf(x[xoff + (long)(mT + rr) * 12]);
    tile[rr][cc] = v;
    Xb[(long)(mT + rr) * 12288 + cg] = v;
  }
  __syncthreads();
  #pragma unroll
  for (int p = 0; p < 16; p++){
    int rr = p * 4 + r;
    Xbt[(long)(cT + rr) * 2048 + mT + cc] = tile[cc][rr];
  }
}

// ---------------- K6: W[n,k,i,o] via float4 + L1 reuse (4 n per block share P slice) ----------------
__global__ __launch_bounds__(256) void k_wb2(const float* __restrict__ E1, const float* __restrict__ E2,
                                             const float* __restrict__ P1, const float* __restrict__ P2,
                                             const float* __restrict__ BP1, const float* __restrict__ BP2,
                                             float* __restrict__ W, float* __restrict__ biasN){
  int bid = blockIdx.x, t = threadIdx.x;
  if (bid < 6144){
    int nb = bid & 511, rb = bid >> 9;       // 512 n-blocks x 12 r-blocks
    int n = nb * 4 + (t >> 6);
    int r4 = rb * 64 + (t & 63);             // float4 index within 768
    const float* e1 = E1 + n * 16;
    const float* e2 = E2 + n * 16;
    f32x4 s = {0.f, 0.f, 0.f, 0.f};
    #pragma unroll
    for (int d = 0; d < 16; d++){
      f32x4 p1 = *(const f32x4*)(P1 + d * 3072 + r4 * 4);
      f32x4 p2 = *(const f32x4*)(P2 + d * 3072 + r4 * 4);
      s += p1 * e1[d] + p2 * e2[d];
    }
    *(f32x4*)(W + (long)n * 3072 + r4 * 4) = s;
  } else {
    int e = (bid - 6144) * 256 + t;          // 65536 bias outputs
    int n = e >> 5, o = e & 31;
    const float* e1 = E1 + n * 16;
    const float* e2 = E2 + n * 16;
    float s = 0.f;
    #pragma unroll
    for (int d = 0; d < 16; d++) s += e1[d] * BP1[d * 32 + o] + e2[d] * BP2[d * 32 + o];
    biasN[e] = s;
  }
}

// ---------------- GEMM: C[m][c] = sum_k A[m][k] * Bt[c][k]; 128x192 tile, 8 waves ----------------
// 2 blocks/CU (80 KiB LDS each): cross-block overlap hides the per-tile
// gate/read window (m114 mechanism; m97 relied on it at 3 blocks/CU).
// Grid 16x64 = 1024 blocks = exactly 2 rounds at 2/CU, zero tail.
// Wave grid 2(m) x 4(n); wave c-cols interleaved across the 3 B regions:
// lc = j*64 + wn*16 + l15, j=0..2. K-tile: one vmcnt(0) gate + one barrier,
// 14 ds_reads up-front, 5 GLOADs staggered between three 8-MFMA clusters.
// acc[4][3]=48 regs. T2 swizzle; T5 setprio; T1 XCD swizzle.
__global__ __launch_bounds__(512, 4) void k_gemm(const u16* __restrict__ A,
                                                 const u16* __restrict__ Bt,
                                                 u16* __restrict__ Cd,
                                                 u16* __restrict__ Ct,
                                                 int writeT){
  // per buffer (u16): A [0,8192) = 128x64, B [8192,20480) = 192x64; buf1 +20480
  __shared__ u16 lds[40960];           // 80 KiB
  int tid  = threadIdx.x;
  int wave = tid >> 6, lane = tid & 63;
  int l15 = lane & 15, q = lane >> 4, l7 = l15 & 7;
  int wm = wave >> 2, wn = wave & 3;   // 2 x 4 waves; wave-tile 64(m) x 48(c, interleaved)

  // bijective XCD swizzle: lin 0..1023; 8 slots per xcd-group share yN
  int lin  = blockIdx.y * 64 + blockIdx.x;   // 0..1023
  int xcd  = lin & 7;
  int slot = lin >> 3;                 // 0..127
  int yN   = slot >> 3;                // 0..15  (m-tile)
  int xN   = (slot & 7) * 8 + xcd;     // 0..63  (c-tile)
  long mBase = (long)yN * 128;
  long cBase = (long)xN * 192;

  f32x4 acc[4][3];
  #pragma unroll
  for (int t2 = 0; t2 < 4; t2++)
    #pragma unroll
    for (int u2 = 0; u2 < 3; u2++) acc[t2][u2] = (f32x4){0.f, 0.f, 0.f, 0.f};

  // staging: per region (64 rows x 64 cols), chunk L = tid -> row = L>>3,
  // c_lds = L&7; source chunk pre-swizzled: cel = (tid&7) ^ ((tid>>3)&7)
  int Lrow = tid >> 3;
  int cel  = (tid & 7) ^ (Lrow & 7);
  const u16* gAp = A  + (mBase + Lrow) * 2048 + cel * 8;
  const u16* gBp = Bt + (cBase + Lrow) * 2048 + cel * 8;

  // A region r in {0,1}: lds[nx + r*4096]; B region r in {0..2}: lds[nx + 8192 + r*4096]
#define GL_A(nx, ko, r) GLOAD16(gAp + (r) * (64 * 2048) + (ko), \
                                lds + (nx) + (r) * 4096 + wave * 512)
#define GL_B(nx, ko, r) GLOAD16(gBp + (r) * (64 * 2048) + (ko), \
                                lds + (nx) + 8192 + (r) * 4096 + wave * 512)

  // all 4 A-frag rows for this wave (rows wm*64 .. wm*64+63)
#define LDA(dst) do { \
    _Pragma("unroll") \
    for (int t2 = 0; t2 < 4; t2++){ \
      int row = wm * 64 + t2 * 16 + l15; \
      _Pragma("unroll") \
      for (int kk = 0; kk < 2; kk++) \
        dst[t2][kk] = *(const bf16x8*)&lds[bA + row * 64 + (((kk << 2) | q) ^ l7) * 8]; \
    } } while(0)

  // B frag for region j: c-local row j*64 + wn*16 + l15
#define LDB(dst, j) do { \
    _Pragma("unroll") \
    for (int kk = 0; kk < 2; kk++) \
      dst[kk] = *(const bf16x8*)&lds[bB + ((j) * 64 + wn * 16 + l15) * 64 + (((kk << 2) | q) ^ l7) * 8]; \
  } while(0)

#define MFMA_Q(AF, BB, j) do { \
    __builtin_amdgcn_s_setprio(1); \
    _Pragma("unroll") \
    for (int t2 = 0; t2 < 4; t2++) \
      _Pragma("unroll") \
      for (int kk = 0; kk < 2; kk++) \
        acc[t2][(j)] = __builtin_amdgcn_mfma_f32_16x16x32_bf16( \
            AF[t2][kk], BB[kk], acc[t2][(j)], 0, 0, 0); \
    __builtin_amdgcn_s_setprio(0); \
  } while(0)

  // prologue: stage tile 0
  GL_A(0, 0, 0); GL_A(0, 0, 1); GL_B(0, 0, 0);
  GL_B(0, 0, 1); GL_B(0, 0, 2);

  for (int t = 0; t < 32; t++){
    const int bufo = (t & 1) ? 20480 : 0;
    const int bA = bufo;
    const int bB = bufo + 8192;
    const int nx = 20480 - bufo;
    const long ko = (long)(t + 1) * 64;
    bf16x8 aA[4][2], bb0[2], bb1[2], bb2[2];
    // ---- gate: own 5 stages of buf[t] retired (had a full K-tile of slack);
    //      barrier makes every wave's stages visible to all ----
    asm volatile("s_waitcnt vmcnt(0)" ::: "memory");
    __builtin_amdgcn_s_barrier();
    // ---- all 14 ds_reads up-front; compiler emits fine-grained lgkmcnt ----
    LDA(aA);
    LDB(bb0, 0);
    LDB(bb1, 1);
    LDB(bb2, 2);
    // ---- clusters with staggered t+1 GLOAD issue between them ----
    if (t < 31){ GL_A(nx, ko, 0); GL_A(nx, ko, 1); GL_B(nx, ko, 0); }
    MFMA_Q(aA, bb0, 0);
    if (t < 31){ GL_B(nx, ko, 1); }
    MFMA_Q(aA, bb1, 1);
    if (t < 31){ GL_B(nx, ko, 2); }
    MFMA_Q(aA, bb2, 2);
    // single end-of-tile barrier is the next iteration's start barrier
  }
  // nothing outstanding (t=31 issued no GLOADs); belt-and-braces before LDS reuse
  asm volatile("s_waitcnt vmcnt(0)" ::: "memory");
  __builtin_amdgcn_sched_barrier(0);
  __syncthreads();

  // ---- epilogue: transposed tile tileT[c][m] in LDS (swizzled), single pass ----
  // row lc (192), 128 m = 16 chunks of 8; chunk'(m,lc) = (m>>3) ^ (lc&7) ^ ((lc>>3)&7)
  // elem off = lc*128 + chunk'*8 + (m&7); tile = 192*128*2B = 48 KB
  #pragma unroll
  for (int t2 = 0; t2 < 4; t2++){
    int m0 = wm * 64 + t2 * 16 + q * 4;
    #pragma unroll
    for (int j = 0; j < 3; j++){
      int lc = j * 64 + wn * 16 + l15;
      ushort4 v = make_ushort4(f2bf(acc[t2][j][0]), f2bf(acc[t2][j][1]),
                               f2bf(acc[t2][j][2]), f2bf(acc[t2][j][3]));
      int sw = ((m0 >> 3) ^ (lc & 7) ^ ((lc >> 3) & 7));
      *(ushort4*)&lds[lc * 128 + (sw << 3) + (m0 & 7)] = v;
    }
  }
  __syncthreads();
  if (writeT){
    // Ct rows are c: 6 passes x 32 rows; 16 lanes x 16B = 256B coalesced per row
    int rr0 = tid >> 4;       // 0..31
    int ch  = tid & 15;       // m-chunk 0..15
    #pragma unroll
    for (int p = 0; p < 6; p++){
      int r = p * 32 + rr0;
      int sw = (ch ^ (r & 7) ^ ((r >> 3) & 7));
      uint4 v = *(const uint4*)&lds[r * 128 + (sw << 3)];
      *(uint4*)&Ct[(cBase + r) * 2048 + mBase + ch * 8] = v;
    }
  }
  {
    // Cd rows are m: gather 8 c-column values per 16B chunk; 24 c-chunks/row
    int rr = tid >> 5;        // 0..15
    int ch = tid & 31;        // c-chunk (use 0..23)
    if (ch < 24){
      #pragma unroll
      for (int p = 0; p < 8; p++){
        int m = p * 16 + rr;
        int msw = (m >> 3), ml = m & 7;
        unsigned w[4];
        #pragma unroll
        for (int jj = 0; jj < 4; jj++){
          int c0 = ch * 8 + jj * 2, c1 = c0 + 1;
          unsigned lo = lds[c0 * 128 + (((msw ^ (c0 & 7) ^ ((c0 >> 3) & 7)) << 3)) + ml];
          unsigned hi = lds[c1 * 128 + (((msw ^ (c1 & 7) ^ ((c1 >> 3) & 7)) << 3)) + ml];
          w[jj] = lo | (hi << 16);
        }
        uint4 v = make_uint4(w[0], w[1], w[2], w[3]);
        *(uint4*)&Cd[(mBase + m) * 12288 + cBase + ch * 8] = v;
      }
    }
  }
#undef GL_A
#undef GL_B
#undef LDA
#undef LDB
#undef MFMA_Q
}

// ---------------- K7: out[b,o,n,s] = bias[n,o] + sum_{k,i} Gk[n,(b,i,s)]*W[n,k,i,o] ----------------
// bf16 LDS (25.6KB, 800B/row pad -> 2-way bank alias = free), uint4 16B staging
// loads, in-loop bf16 unpack. ~30KB LDS -> 5 blocks/CU.
__global__ __launch_bounds__(256, 4) void k_final(const u16* __restrict__ G0,
                                                  const u16* __restrict__ G1,
                                                  const u16* __restrict__ G2,
                                                  const float* __restrict__ W,
                                                  const float* __restrict__ biasN,
                                                  float* __restrict__ out){
  __shared__ __align__(16) u16 gs[32 * 400];   // per-b row: 384 bf16 + 16 pad
  __shared__ __align__(16) float ws4[1024];    // W[n][k] slice [i=32][o=32]
  __shared__ float bbuf[32];
  int bid = blockIdx.x;
  int n = (bid & 7) * 256 + (bid >> 3);   // XCD-swizzle: adjacent n share an XCD L2
  int t = threadIdx.x;
  int b = t >> 3, oc = t & 7;
  f32x4 acc[4][3];                         // [jo: o=oc+8*jo][s-quad]
  #pragma unroll
  for (int jo = 0; jo < 4; jo++)
    #pragma unroll
    for (int v = 0; v < 3; v++) acc[jo][v] = (f32x4){0.f, 0.f, 0.f, 0.f};

  const u16* srcs[3] = {G0, G1, G2};
  for (int k = 0; k < 3; k++){
    __syncthreads();
    // stage G[n] slab: 12288 bf16 = 1536 x 16B chunks; 48 chunks per b-row
    const uint4* src = (const uint4*)(srcs[k] + (long)n * 12288);
    #pragma unroll
    for (int p = 0; p < 6; p++){
      int c = t + p * 256;
      int br = c / 48, wi = c - br * 48;
      *(uint4*)&gs[br * 400 + wi * 8] = src[c];
    }
    const float4* wsrc = (const float4*)(W + (long)n * 3072 + k * 1024);
    *(float4*)&ws4[t * 4] = wsrc[t];
    if (k == 0 && t < 8) *(float4*)&bbuf[t * 4] = ((const float4*)(biasN + (long)n * 32))[t];
    __syncthreads();

    const u16* gp = gs + b * 400;
    #pragma unroll 4
    for (int ii = 0; ii < 16; ii++){       // two i per iter: i0=2ii, i1=2ii+1
      uint4 A  = *(const uint4*)&gp[ii * 24];
      uint4 Bc = *(const uint4*)&gp[ii * 24 + 8];
      uint4 Cc = *(const uint4*)&gp[ii * 24 + 16];
      float2 p0 = unp2(A.x),  p1 = unp2(A.y),  p2 = unp2(A.z),  p3 = unp2(A.w);
      float2 p4 = unp2(Bc.x), p5 = unp2(Bc.y), p6 = unp2(Bc.z), p7 = unp2(Bc.w);
      float2 p8 = unp2(Cc.x), p9 = unp2(Cc.y), pa = unp2(Cc.z), pb = unp2(Cc.w);
      f32x4 G0v0 = (f32x4){p0.x, p0.y, p1.x, p1.y};
      f32x4 G0v1 = (f32x4){p2.x, p2.y, p3.x, p3.y};
      f32x4 G0v2 = (f32x4){p4.x, p4.y, p5.x, p5.y};
      f32x4 G1v0 = (f32x4){p6.x, p6.y, p7.x, p7.y};
      f32x4 G1v1 = (f32x4){p8.x, p8.y, p9.x, p9.y};
      f32x4 G1v2 = (f32x4){pa.x, pa.y, pb.x, pb.y};
      #pragma unroll
      for (int jo = 0; jo < 4; jo++){
        float w0 = ws4[(ii * 2)     * 32 + oc + jo * 8];   // broadcast reads
        float w1 = ws4[(ii * 2 + 1) * 32 + oc + jo * 8];
        acc[jo][0] += G0v0 * w0;
        acc[jo][1] += G0v1 * w0;
        acc[jo][2] += G0v2 * w0;
        acc[jo][0] += G1v0 * w1;
        acc[jo][1] += G1v1 * w1;
        acc[jo][2] += G1v2 * w1;
      }
    }
  }
  #pragma unroll
  for (int jo = 0; jo < 4; jo++){
    int o = oc + jo * 8;
    float bv = bbuf[o];
    f32x4 bs = {bv, bv, bv, bv};
    long base = ((long)(b * 32 + o) * 2048 + n) * 12;
    *(f32x4*)(out + base)     = acc[jo][0] + bs;
    *(f32x4*)(out + base + 4) = acc[jo][1] + bs;
    *(f32x4*)(out + base + 8) = acc[jo][2] + bs;
  }
}

extern "C" void kernel_launch(void* const* d_in, const int* in_sizes, int n_in,
                              void* d_out, int out_size, void* d_ws, size_t ws_size,
                              hipStream_t stream){
  const float* x    = (const float*)d_in[0];
  const float* E1   = (const float*)d_in[1];
  const float* E2   = (const float*)d_in[2];
  const float* P1   = (const float*)d_in[3];
  const float* P2   = (const float*)d_in[4];
  const float* BP1  = (const float*)d_in[5];
  const float* BP2  = (const float*)d_in[6];
  const float* fc0w = (const float*)d_in[7];
  const float* fc0b = (const float*)d_in[8];
  const float* fc1w = (const float*)d_in[9];
  const float* fc1b = (const float*)d_in[10];
  const float* fc2w = (const float*)d_in[11];
  const float* fc2b = (const float*)d_in[12];
  float* out = (float*)d_out;

  char* ws = (char*)d_ws;
  size_t off = 0;
  auto carve = [&](size_t bytes) -> char* {
    char* p = ws + off;
    off += (bytes + 255) & ~(size_t)255;
    return p;
  };
  float* h1            = (float*)carve((size_t)65536 * 4);
  float* h2raw         = (float*)carve((size_t)512 * 4);
  float* mmat          = (float*)carve((size_t)256 * 4);
  u16* sup             = (u16*)carve((size_t)2048 * 2048 * 2);
  u16* Xbt             = (u16*)carve((size_t)12288 * 2048 * 2);
  u16* Xb              = (u16*)carve((size_t)2048 * 12288 * 2);
  u16* G1t             = (u16*)carve((size_t)12288 * 2048 * 2);
  u16* G1              = (u16*)carve((size_t)2048 * 12288 * 2);
  float* W             = (float*)carve((size_t)2048 * 3072 * 4);
  float* biasN         = (float*)carve((size_t)2048 * 32 * 4);
  u16* G2              = Xbt;   // alias: Xbt dead after GEMM1, GEMM2 writes G2 here
  (void)ws_size; (void)in_sizes; (void)n_in; (void)out_size;

  k_h1     <<<256, 256, 0, stream>>>(x, fc0w, fc0b, h1);
  k_h2a    <<<512, 256, 0, stream>>>(h1, fc1w, h2raw);
  k_h2b    <<<1, 512, 0, stream>>>(h2raw, fc1b, fc2w, fc2b, mmat);
  k_support<<<2048, 256, 0, stream>>>(E1, E2, mmat, sup);
  k_xbt2   <<<dim3(192, 32), 256, 0, stream>>>(x, Xb, Xbt);
  k_wb2    <<<6400, 256, 0, stream>>>(E1, E2, P1, P2, BP1, BP2, W, biasN);
  k_gemm   <<<dim3(64, 16), 512, 0, stream>>>(sup, Xbt, G1, G1t, 1);   // G1 = S@X
  k_gemm   <<<dim3(64, 16), 512, 0, stream>>>(sup, G1t, G2, G1t, 0);   // G2 = S@G1
  k_final  <<<2048, 256, 0, stream>>>(Xb, G1, G2, W, biasN, out);
}